// Round 16
// baseline (203.610 us; speedup 1.0000x reference)
//
#include <hip/hip_runtime.h>
#include <hip/hip_bf16.h>

#define N_NODES 100000
#define NUM_APS 1000
#define IN_F 32
#define HID 64
#define NB 391      // bins of 256 cols: 391*256 = 100096 >= N_NODES
#define EPB 1024    // edges per block in binning pass (was 4096: 12% occupancy)
#define CAPB 4608   // per-bin staging capacity (mean 4092, +8 sigma), guarded
#define LISTCAP 24000

typedef __hip_bfloat16 bf16;
typedef unsigned long long ull;
typedef __attribute__((ext_vector_type(8))) short bf16x8;
typedef __attribute__((ext_vector_type(4))) float f32x4;

__device__ __forceinline__ float b2f(bf16 v) { return __bfloat162float(v); }
__device__ __forceinline__ float blo(unsigned u) { return __uint_as_float(u << 16); }
__device__ __forceinline__ float bhi(unsigned u) { return __uint_as_float(u & 0xffff0000u); }
__device__ __forceinline__ unsigned packbf(float x, float y) {
    bf16 a = __float2bfloat16(x), b = __float2bfloat16(y);
    unsigned short ua = *reinterpret_cast<unsigned short*>(&a);
    unsigned short ub = *reinterpret_cast<unsigned short*>(&b);
    return (unsigned)ua | ((unsigned)ub << 16);
}
__device__ __forceinline__ short f2bs(float v) {
    bf16 t = __float2bfloat16(v);
    return *reinterpret_cast<short*>(&t);
}
// 4B edge record: r<<15 | q15(ew)
__device__ __forceinline__ unsigned rec_r(unsigned v) { return v >> 15; }
__device__ __forceinline__ float rec_w(unsigned v) { return (v & 32767u) * (1.f / 32768.f); }

// ---------- binned CSR build, hist-free ----------
__global__ __launch_bounds__(256) void binwrite2_k(const int* __restrict__ row,
                                                   const int* __restrict__ col,
                                                   const float* __restrict__ ew,
                                                   int* __restrict__ binPtr,
                                                   ull* __restrict__ staging, int E) {
    __shared__ int h1[NB];
    __shared__ int base[NB];
    __shared__ int h2[NB];
    for (int i = threadIdx.x; i < NB; i += 256) { h1[i] = 0; h2[i] = 0; }
    __syncthreads();
    int e0 = blockIdx.x * EPB, e1 = min(e0 + EPB, E);
    for (int e = e0 + threadIdx.x; e < e1; e += 256) atomicAdd(&h1[col[e] >> 8], 1);
    __syncthreads();
    for (int i = threadIdx.x; i < NB; i += 256) {
        int v = h1[i];
        base[i] = v ? atomicAdd(&binPtr[i], v) : 0;
    }
    __syncthreads();
    for (int e = e0 + threadIdx.x; e < e1; e += 256) {
        int c = col[e];
        int b = c >> 8;
        int slot = atomicAdd(&h2[b], 1);
        unsigned q = (unsigned)(ew[e] * 32768.0f + 0.5f);
        if (q > 32767u) q = 32767u;
        ull rec = ((ull)(unsigned)(c & 255) << 32) |
                  (ull)(((unsigned)row[e] << 15) | q);
        int pos = base[b] + slot;
        if (pos < CAPB) staging[(size_t)b * CAPB + pos] = rec;
    }
}

__global__ __launch_bounds__(512) void binscan2_k(const int* __restrict__ binPtr,
                                                  int* __restrict__ binBase) {
    __shared__ int s[512];
    int v = (threadIdx.x < NB) ? min(binPtr[threadIdx.x], CAPB) : 0;
    s[threadIdx.x] = v;
    __syncthreads();
    for (int d = 1; d < 512; d <<= 1) {
        int t = (threadIdx.x >= d) ? s[threadIdx.x - d] : 0;
        __syncthreads();
        s[threadIdx.x] += t;
        __syncthreads();
    }
    if (threadIdx.x <= NB) binBase[threadIdx.x] = s[threadIdx.x] - v;
}

__global__ __launch_bounds__(256) void binfin2_k(const ull* __restrict__ staging,
                                                 const int* __restrict__ binBase,
                                                 unsigned* __restrict__ ed,
                                                 int* __restrict__ off,
                                                 float* __restrict__ dinv) {
    __shared__ unsigned cnt[256];
    __shared__ unsigned degq[256];
    __shared__ int wptr[256];
    __shared__ unsigned s[256];
    int b = blockIdx.x;
    int e0 = binBase[b];
    int cntb = binBase[b + 1] - e0;
    const ull* st = staging + (size_t)b * CAPB;
    cnt[threadIdx.x] = 0;
    degq[threadIdx.x] = 0;
    __syncthreads();
    for (int i = threadIdx.x; i < cntb; i += 256) {
        ull rec = st[i];
        unsigned cl = (unsigned)(rec >> 32) & 255u;
        atomicAdd(&cnt[cl], 1u);
        atomicAdd(&degq[cl], (unsigned)rec & 32767u);
    }
    __syncthreads();
    unsigned v = cnt[threadIdx.x];
    s[threadIdx.x] = v;
    __syncthreads();
    for (int d = 1; d < 256; d <<= 1) {
        unsigned t = (threadIdx.x >= d) ? s[threadIdx.x - d] : 0;
        __syncthreads();
        s[threadIdx.x] += t;
        __syncthreads();
    }
    int colg = (b << 8) + threadIdx.x;
    if (colg < N_NODES) {
        off[colg] = e0 + (int)s[threadIdx.x];  // segment END
        float deg = (float)degq[threadIdx.x] * (1.0f / 32768.0f);
        dinv[colg] = deg > 0.f ? 1.0f / sqrtf(deg) : 0.f;
    }
    wptr[threadIdx.x] = e0 + (int)s[threadIdx.x] - (int)v;  // exclusive start
    __syncthreads();
    for (int i = threadIdx.x; i < cntb; i += 256) {
        ull rec = st[i];
        unsigned cl = (unsigned)(rec >> 32) & 255u;
        int pos = atomicAdd(&wptr[cl], 1);
        ed[pos] = (unsigned)rec;  // low 32 bits = r<<15 | q15
    }
}

// ---------- active set (verbatim) ----------
__global__ __launch_bounds__(256) void activeset_k(const unsigned* __restrict__ ed,
                                                   const int* __restrict__ off,
                                                   int* __restrict__ mark,
                                                   int* __restrict__ list,
                                                   int* __restrict__ cnt) {
    int e = blockIdx.x * 256 + threadIdx.x;
    int end = off[NUM_APS - 1];
    if (e >= end) return;
    int r = (int)rec_r(ed[e]);
    if (atomicExch(&mark[r], 1) == 0) {
        int pos = atomicAdd(cnt, 1);
        if (pos < LISTCAP) list[pos] = r;
    }
}

// xs = dinv ⊙ x, to bf16  (verbatim)
__global__ void xs_k(const float* __restrict__ x, const float* __restrict__ dinv,
                     bf16* __restrict__ xb, int n) {
    int i = blockIdx.x * blockDim.x + threadIdx.x;
    if (i >= n) return;
    xb[i] = __float2bfloat16(x[i] * dinv[i >> 5]);
}

// ---------- 32-feat gathers: 4 lanes/node, uint4 loads (verbatim round 14) ----------
__global__ __launch_bounds__(256) void gath32_dual_k(const unsigned* __restrict__ ed,
                                                     const int* __restrict__ off,
                                                     const float* __restrict__ dinv,
                                                     const uint4* __restrict__ src4,
                                                     uint4* __restrict__ p4,
                                                     uint4* __restrict__ u4, int nn) {
    int t = blockIdx.x * 256 + threadIdx.x;
    int n = t >> 2;
    if (n >= nn) return;
    int qd = t & 3;
    int s = (n == 0) ? 0 : off[n - 1];
    int e = off[n];
    float aA[8] = {0,0,0,0,0,0,0,0};
    float aB[8] = {0,0,0,0,0,0,0,0};
    float aC[8] = {0,0,0,0,0,0,0,0};
    float aD[8] = {0,0,0,0,0,0,0,0};
    int i = s;
    for (; i + 4 <= e; i += 4) {
        unsigned v0 = ed[i], v1 = ed[i + 1], v2 = ed[i + 2], v3 = ed[i + 3];
        uint4 s0 = src4[rec_r(v0) * 4 + qd];
        uint4 s1 = src4[rec_r(v1) * 4 + qd];
        uint4 s2 = src4[rec_r(v2) * 4 + qd];
        uint4 s3 = src4[rec_r(v3) * 4 + qd];
        float w0 = rec_w(v0), w1 = rec_w(v1), w2 = rec_w(v2), w3 = rec_w(v3);
        aA[0] += w0 * blo(s0.x); aA[1] += w0 * bhi(s0.x);
        aA[2] += w0 * blo(s0.y); aA[3] += w0 * bhi(s0.y);
        aA[4] += w0 * blo(s0.z); aA[5] += w0 * bhi(s0.z);
        aA[6] += w0 * blo(s0.w); aA[7] += w0 * bhi(s0.w);
        aB[0] += w1 * blo(s1.x); aB[1] += w1 * bhi(s1.x);
        aB[2] += w1 * blo(s1.y); aB[3] += w1 * bhi(s1.y);
        aB[4] += w1 * blo(s1.z); aB[5] += w1 * bhi(s1.z);
        aB[6] += w1 * blo(s1.w); aB[7] += w1 * bhi(s1.w);
        aC[0] += w2 * blo(s2.x); aC[1] += w2 * bhi(s2.x);
        aC[2] += w2 * blo(s2.y); aC[3] += w2 * bhi(s2.y);
        aC[4] += w2 * blo(s2.z); aC[5] += w2 * bhi(s2.z);
        aC[6] += w2 * blo(s2.w); aC[7] += w2 * bhi(s2.w);
        aD[0] += w3 * blo(s3.x); aD[1] += w3 * bhi(s3.x);
        aD[2] += w3 * blo(s3.y); aD[3] += w3 * bhi(s3.y);
        aD[4] += w3 * blo(s3.z); aD[5] += w3 * bhi(s3.z);
        aD[6] += w3 * blo(s3.w); aD[7] += w3 * bhi(s3.w);
    }
    for (; i < e; ++i) {
        unsigned v = ed[i];
        uint4 sv = src4[rec_r(v) * 4 + qd];
        float w = rec_w(v);
        aA[0] += w * blo(sv.x); aA[1] += w * bhi(sv.x);
        aA[2] += w * blo(sv.y); aA[3] += w * bhi(sv.y);
        aA[4] += w * blo(sv.z); aA[5] += w * bhi(sv.z);
        aA[6] += w * blo(sv.w); aA[7] += w * bhi(sv.w);
    }
#pragma unroll
    for (int k = 0; k < 8; ++k) aA[k] += aB[k] + aC[k] + aD[k];
    float d = dinv[n], d2 = d * d;
    p4[n * 4 + qd] = make_uint4(packbf(d * aA[0], d * aA[1]), packbf(d * aA[2], d * aA[3]),
                                packbf(d * aA[4], d * aA[5]), packbf(d * aA[6], d * aA[7]));
    u4[n * 4 + qd] = make_uint4(packbf(d2 * aA[0], d2 * aA[1]), packbf(d2 * aA[2], d2 * aA[3]),
                                packbf(d2 * aA[4], d2 * aA[5]), packbf(d2 * aA[6], d2 * aA[7]));
}

__global__ __launch_bounds__(256) void gath32_one_k(const unsigned* __restrict__ ed,
                                                    const int* __restrict__ off,
                                                    const float* __restrict__ dinv,
                                                    const uint4* __restrict__ src4,
                                                    uint4* __restrict__ p4, int nn) {
    int t = blockIdx.x * 256 + threadIdx.x;
    int n = t >> 2;
    if (n >= nn) return;
    int qd = t & 3;
    int s = (n == 0) ? 0 : off[n - 1];
    int e = off[n];
    float aA[8] = {0,0,0,0,0,0,0,0};
    float aB[8] = {0,0,0,0,0,0,0,0};
    float aC[8] = {0,0,0,0,0,0,0,0};
    float aD[8] = {0,0,0,0,0,0,0,0};
    int i = s;
    for (; i + 4 <= e; i += 4) {
        unsigned v0 = ed[i], v1 = ed[i + 1], v2 = ed[i + 2], v3 = ed[i + 3];
        uint4 s0 = src4[rec_r(v0) * 4 + qd];
        uint4 s1 = src4[rec_r(v1) * 4 + qd];
        uint4 s2 = src4[rec_r(v2) * 4 + qd];
        uint4 s3 = src4[rec_r(v3) * 4 + qd];
        float w0 = rec_w(v0), w1 = rec_w(v1), w2 = rec_w(v2), w3 = rec_w(v3);
        aA[0] += w0 * blo(s0.x); aA[1] += w0 * bhi(s0.x);
        aA[2] += w0 * blo(s0.y); aA[3] += w0 * bhi(s0.y);
        aA[4] += w0 * blo(s0.z); aA[5] += w0 * bhi(s0.z);
        aA[6] += w0 * blo(s0.w); aA[7] += w0 * bhi(s0.w);
        aB[0] += w1 * blo(s1.x); aB[1] += w1 * bhi(s1.x);
        aB[2] += w1 * blo(s1.y); aB[3] += w1 * bhi(s1.y);
        aB[4] += w1 * blo(s1.z); aB[5] += w1 * bhi(s1.z);
        aB[6] += w1 * blo(s1.w); aB[7] += w1 * bhi(s1.w);
        aC[0] += w2 * blo(s2.x); aC[1] += w2 * bhi(s2.x);
        aC[2] += w2 * blo(s2.y); aC[3] += w2 * bhi(s2.y);
        aC[4] += w2 * blo(s2.z); aC[5] += w2 * bhi(s2.z);
        aC[6] += w2 * blo(s2.w); aC[7] += w2 * bhi(s2.w);
        aD[0] += w3 * blo(s3.x); aD[1] += w3 * bhi(s3.x);
        aD[2] += w3 * blo(s3.y); aD[3] += w3 * bhi(s3.y);
        aD[4] += w3 * blo(s3.z); aD[5] += w3 * bhi(s3.z);
        aD[6] += w3 * blo(s3.w); aD[7] += w3 * bhi(s3.w);
    }
    for (; i < e; ++i) {
        unsigned v = ed[i];
        uint4 sv = src4[rec_r(v) * 4 + qd];
        float w = rec_w(v);
        aA[0] += w * blo(sv.x); aA[1] += w * bhi(sv.x);
        aA[2] += w * blo(sv.y); aA[3] += w * bhi(sv.y);
        aA[4] += w * blo(sv.z); aA[5] += w * bhi(sv.z);
        aA[6] += w * blo(sv.w); aA[7] += w * bhi(sv.w);
    }
#pragma unroll
    for (int k = 0; k < 8; ++k) aA[k] += aB[k] + aC[k] + aD[k];
    float d = dinv[n];
    p4[n * 4 + qd] = make_uint4(packbf(d * aA[0], d * aA[1]), packbf(d * aA[2], d * aA[3]),
                                packbf(d * aA[4], d * aA[5]), packbf(d * aA[6], d * aA[7]));
}

// ---------- 64-feat gathers (verbatim, pruned domain) ----------
__global__ __launch_bounds__(256) void gath64_q1_k(const unsigned* __restrict__ ed,
                                                   const int* __restrict__ off,
                                                   const float* __restrict__ dinv,
                                                   const unsigned* __restrict__ src,
                                                   unsigned* __restrict__ u,
                                                   unsigned* __restrict__ q, int nn) {
    int t = blockIdx.x * 256 + threadIdx.x;
    int n = t >> 5;
    if (n >= nn) return;
    int fp = t & 31;
    int s = (n == 0) ? 0 : off[n - 1];
    int e = off[n];
    float a0 = 0.f, a1 = 0.f, b0 = 0.f, b1 = 0.f;
    int i = s;
    for (; i + 4 <= e; i += 4) {
        unsigned v0 = ed[i], v1 = ed[i + 1], v2 = ed[i + 2], v3 = ed[i + 3];
        unsigned s0 = src[rec_r(v0) * 32 + fp];
        unsigned s1 = src[rec_r(v1) * 32 + fp];
        unsigned s2 = src[rec_r(v2) * 32 + fp];
        unsigned s3 = src[rec_r(v3) * 32 + fp];
        float w0 = rec_w(v0), w1 = rec_w(v1), w2 = rec_w(v2), w3 = rec_w(v3);
        a0 += w0 * blo(s0); a1 += w0 * bhi(s0);
        b0 += w1 * blo(s1); b1 += w1 * bhi(s1);
        a0 += w2 * blo(s2); a1 += w2 * bhi(s2);
        b0 += w3 * blo(s3); b1 += w3 * bhi(s3);
    }
    for (; i < e; ++i) {
        unsigned v = ed[i];
        unsigned sv = src[rec_r(v) * 32 + fp];
        float w = rec_w(v);
        a0 += w * blo(sv); a1 += w * bhi(sv);
    }
    a0 += b0; a1 += b1;
    float d = dinv[n], d2 = d * d;
    u[n * 32 + fp] = packbf(d2 * a0, d2 * a1);
    q[n * 32 + fp] = packbf(d * a0, d * a1);
}

__global__ __launch_bounds__(256) void gath64_act_k(const unsigned* __restrict__ ed,
                                                    const int* __restrict__ off,
                                                    const float* __restrict__ dinv,
                                                    const unsigned* __restrict__ src,
                                                    const int* __restrict__ list,
                                                    const int* __restrict__ cnt,
                                                    unsigned* __restrict__ u) {
    int t = blockIdx.x * 256 + threadIdx.x;
    int idx = t >> 5;
    int c = *cnt;
    if (c > LISTCAP) c = LISTCAP;
    if (idx >= c) return;
    int n = list[idx];
    int fp = t & 31;
    int s = (n == 0) ? 0 : off[n - 1];
    int e = off[n];
    float a0 = 0.f, a1 = 0.f, b0 = 0.f, b1 = 0.f;
    int i = s;
    for (; i + 4 <= e; i += 4) {
        unsigned v0 = ed[i], v1 = ed[i + 1], v2 = ed[i + 2], v3 = ed[i + 3];
        unsigned s0 = src[rec_r(v0) * 32 + fp];
        unsigned s1 = src[rec_r(v1) * 32 + fp];
        unsigned s2 = src[rec_r(v2) * 32 + fp];
        unsigned s3 = src[rec_r(v3) * 32 + fp];
        float w0 = rec_w(v0), w1 = rec_w(v1), w2 = rec_w(v2), w3 = rec_w(v3);
        a0 += w0 * blo(s0); a1 += w0 * bhi(s0);
        b0 += w1 * blo(s1); b1 += w1 * bhi(s1);
        a0 += w2 * blo(s2); a1 += w2 * bhi(s2);
        b0 += w3 * blo(s3); b1 += w3 * bhi(s3);
    }
    for (; i < e; ++i) {
        unsigned v = ed[i];
        unsigned sv = src[rec_r(v) * 32 + fp];
        float w = rec_w(v);
        a0 += w * blo(sv); a1 += w * bhi(sv);
    }
    a0 += b0; a1 += b1;
    float d = dinv[n], d2 = d * d;
    u[n * 32 + fp] = packbf(d2 * a0, d2 * a1);
}

__global__ __launch_bounds__(256) void gath64_one_k(const unsigned* __restrict__ ed,
                                                    const int* __restrict__ off,
                                                    const float* __restrict__ dinv,
                                                    const unsigned* __restrict__ src,
                                                    unsigned* __restrict__ q, int nn) {
    int t = blockIdx.x * 256 + threadIdx.x;
    int n = t >> 5;
    if (n >= nn) return;
    int fp = t & 31;
    int s = (n == 0) ? 0 : off[n - 1];
    int e = off[n];
    float a0 = 0.f, a1 = 0.f, b0 = 0.f, b1 = 0.f;
    int i = s;
    for (; i + 4 <= e; i += 4) {
        unsigned v0 = ed[i], v1 = ed[i + 1], v2 = ed[i + 2], v3 = ed[i + 3];
        unsigned s0 = src[rec_r(v0) * 32 + fp];
        unsigned s1 = src[rec_r(v1) * 32 + fp];
        unsigned s2 = src[rec_r(v2) * 32 + fp];
        unsigned s3 = src[rec_r(v3) * 32 + fp];
        float w0 = rec_w(v0), w1 = rec_w(v1), w2 = rec_w(v2), w3 = rec_w(v3);
        a0 += w0 * blo(s0); a1 += w0 * bhi(s0);
        b0 += w1 * blo(s1); b1 += w1 * bhi(s1);
        a0 += w2 * blo(s2); a1 += w2 * bhi(s2);
        b0 += w3 * blo(s3); b1 += w3 * bhi(s3);
    }
    for (; i < e; ++i) {
        unsigned v = ed[i];
        unsigned sv = src[rec_r(v) * 32 + fp];
        float w = rec_w(v);
        a0 += w * blo(sv); a1 += w * bhi(sv);
    }
    a0 += b0; a1 += b1;
    float d = dinv[n];
    q[n * 32 + fp] = packbf(d * a0, d * a1);
}

// ---------- dense layer 1 on MFMA (verbatim round 15, verified) ----------
__global__ __launch_bounds__(256) void dense1m_k(const float* __restrict__ x,
                                                 const unsigned* __restrict__ p1,
                                                 const unsigned* __restrict__ p2,
                                                 const float* __restrict__ w,
                                                 const float* __restrict__ b,
                                                 const float* __restrict__ dinv,
                                                 bf16* __restrict__ h1s,
                                                 bf16* __restrict__ h1p) {
    __shared__ short sxb[64 * 104];   // inputs bf16 [node][k], 13.3 KB
    __shared__ short swt[64 * 104];   // weights^T bf16 [col][k], 13.3 KB
    __shared__ float sbias[64];
    __shared__ float sdv[64];
    int tid = threadIdx.x;
    int nb = blockIdx.x * 64;
    for (int idx = tid; idx < 96 * 64; idx += 256) {
        int j = idx >> 6, f = idx & 63;
        swt[f * 104 + j] = f2bs(w[idx]);
    }
    for (int i = tid; i < 64 * 16; i += 256) {
        int n = i >> 4, c = i & 15;
        int gn = nb + n;
        float v0 = 0.f, v1 = 0.f;
        if (gn < N_NODES) {
            v0 = x[(size_t)gn * 32 + 2 * c];
            v1 = x[(size_t)gn * 32 + 2 * c + 1];
        }
        ((unsigned*)sxb)[n * 52 + c] = packbf(v0, v1);
    }
    for (int i = tid; i < 64 * 16; i += 256) {
        int n = i >> 4, c = i & 15;
        int gn = nb + n;
        unsigned v1 = 0u, v2 = 0u;
        if (gn < N_NODES) {
            v1 = p1[(size_t)gn * 16 + c];
            v2 = p2[(size_t)gn * 16 + c];
        }
        ((unsigned*)sxb)[n * 52 + 16 + c] = v1;
        ((unsigned*)sxb)[n * 52 + 32 + c] = v2;
    }
    if (tid < 64) {
        sbias[tid] = b[tid];
        int gn = nb + tid;
        sdv[tid] = (gn < N_NODES) ? dinv[gn] : 0.f;
    }
    __syncthreads();

    int lane = tid & 63;
    int wt = tid >> 6;
    int lr = lane & 15;
    int kg = lane >> 4;
    const short* arow = &sxb[(wt * 16 + lr) * 104 + kg * 8];
    bf16x8 a0 = *(const bf16x8*)(arow);
    bf16x8 a1 = *(const bf16x8*)(arow + 32);
    bf16x8 a2 = *(const bf16x8*)(arow + 64);
#pragma unroll
    for (int ct = 0; ct < 4; ++ct) {
        const short* bcol = &swt[(ct * 16 + lr) * 104 + kg * 8];
        bf16x8 b0 = *(const bf16x8*)(bcol);
        bf16x8 b1 = *(const bf16x8*)(bcol + 32);
        bf16x8 b2 = *(const bf16x8*)(bcol + 64);
        f32x4 acc = {0.f, 0.f, 0.f, 0.f};
        acc = __builtin_amdgcn_mfma_f32_16x16x32_bf16(a0, b0, acc, 0, 0, 0);
        acc = __builtin_amdgcn_mfma_f32_16x16x32_bf16(a1, b1, acc, 0, 0, 0);
        acc = __builtin_amdgcn_mfma_f32_16x16x32_bf16(a2, b2, acc, 0, 0, 0);
        int colo = ct * 16 + lr;
        float bias = sbias[colo];
#pragma unroll
        for (int r = 0; r < 4; ++r) {
            int rowl = wt * 16 + kg * 4 + r;
            int gn = nb + rowl;
            if (gn < N_NODES) {
                float a = acc[r] + bias;
                a = a > 0.f ? a : 0.01f * a;
                h1s[(size_t)gn * HID + colo] = __float2bfloat16(a * sdv[rowl]);
                if (gn < NUM_APS) h1p[(size_t)gn * HID + colo] = __float2bfloat16(a);
            }
        }
    }
}

// dense2 (verbatim)
__global__ __launch_bounds__(256) void dense2_k(const bf16* __restrict__ h1p,
                                                const bf16* __restrict__ q1,
                                                const bf16* __restrict__ q2,
                                                const float* __restrict__ w,
                                                const float* __restrict__ b,
                                                float* __restrict__ ap) {
    __shared__ float sw[3 * HID * HID];  // 48 KB
    __shared__ float sx[4][3 * HID];
    for (int i = threadIdx.x; i < 3 * HID * HID; i += 256) sw[i] = w[i];
    int nb = blockIdx.x * 4;
    for (int k = threadIdx.x; k < 4 * 192; k += 256) {
        int ln = k / 192, j = k % 192;
        int n = nb + ln;
        float v = 0.f;
        if (n < NUM_APS) {
            int hop = j >> 6, ii = j & 63;
            const bf16* sp = (hop == 0) ? h1p : (hop == 1 ? q1 : q2);
            v = b2f(sp[n * HID + ii]);
        }
        sx[ln][j] = v;
    }
    __syncthreads();
    int ln = threadIdx.x >> 6;
    int n = nb + ln;
    if (n >= NUM_APS) return;
    int f = threadIdx.x & 63;
    float acc = b[f];
#pragma unroll 8
    for (int j = 0; j < 192; ++j) acc += sx[ln][j] * sw[j * HID + f];
    acc = acc > 0.f ? acc : 0.01f * acc;
    ap[n * HID + f] = acc;
}

// two 64->3 heads (verbatim)
__global__ void logits_k(const float* __restrict__ ap,
                         const float* __restrict__ wch, const float* __restrict__ bch,
                         const float* __restrict__ wpw, const float* __restrict__ bpw,
                         float* __restrict__ out) {
    int idx = blockIdx.x * blockDim.x + threadIdx.x;
    if (idx >= NUM_APS * 6) return;
    int n = idx / 6, j = idx % 6;
    const float* w;
    float bb;
    float* o;
    if (j < 3) {
        w = wch + j; bb = bch[j]; o = out + n * 3 + j;
    } else {
        int jj = j - 3;
        w = wpw + jj; bb = bpw[jj]; o = out + NUM_APS * 3 + n * 3 + jj;
    }
    float acc = bb;
    const float* a = ap + n * HID;
#pragma unroll
    for (int i = 0; i < HID; ++i) acc += a[i] * w[i * 3];
    *o = acc;
}

extern "C" void kernel_launch(void* const* d_in, const int* in_sizes, int n_in,
                              void* d_out, int out_size, void* d_ws, size_t ws_size,
                              hipStream_t stream) {
    const float* x   = (const float*)d_in[0];
    const int*   ei  = (const int*)d_in[1];
    const float* ea  = (const float*)d_in[2];
    const float* w1  = (const float*)d_in[3];
    const float* b1  = (const float*)d_in[4];
    const float* w2  = (const float*)d_in[5];
    const float* b2  = (const float*)d_in[6];
    const float* wch = (const float*)d_in[7];
    const float* bch = (const float*)d_in[8];
    const float* wpw = (const float*)d_in[9];
    const float* bpw = (const float*)d_in[10];

    const int E = in_sizes[2];  // 1,600,000
    const int* row  = ei;
    const int* colv = ei + E;

    // ---- workspace layout (4-byte units), ~48.2 MB (verbatim round 15) ----
    float* ws = (float*)d_ws;
    ull*      staging = (ull*)ws;                     // [0, 3,603,456)
    int*      mark    = (int*)ws;                     // 100,000 ints (overlays staging)
    int*      acnt    = (int*)(ws + 100000);          // 1 int
    int*      alist   = (int*)(ws + 100001);          // LISTCAP ints
    unsigned* ed      = (unsigned*)(ws + 3700000);    // [3.7M, 5.3M)
    int*      binPtr  = (int*)(ws + 5300000);         // 512
    int*      binBase = (int*)(ws + 5300512);         // 512 (needs NB+1)
    int*      off     = (int*)(ws + 5301024);         // +100,000
    float*    dinv    = ws + 5401024;                 // +100,000
    unsigned* xs      = (unsigned*)(ws + 5501024);    // 1.6M (16B-aligned)
    unsigned* u1      = xs + 1600000;                 // 1.6M
    unsigned* p1      = (unsigned*)(ws + 8701024);    // 1.6M
    unsigned* p2      = p1 + 1600000;                 // 1.6M
    unsigned* h1s     = xs;                           // overlays xs∪u1 (3.2M)
    unsigned* u3      = p1;                           // overlays p1∪p2 (3.2M)
    bf16*     h1p     = (bf16*)(ws + 11901024);       // 32K units
    bf16*     q1      = (bf16*)(ws + 11933024);       // 32K
    bf16*     q2      = (bf16*)(ws + 11965024);       // 32K
    float*    ap      = ws + 11997024;                // 64K

    const int gridE = (E + EPB - 1) / EPB;  // 1563 for E=1.6M

    // ---- hist-free binned CSR build ----
    hipMemsetAsync(binPtr, 0, 512 * sizeof(int), stream);
    binwrite2_k<<<gridE, 256, 0, stream>>>(row, colv, ea, binPtr, staging, E);
    binscan2_k<<<1, 512, 0, stream>>>(binPtr, binBase);
    binfin2_k<<<NB, 256, 0, stream>>>(staging, binBase, ed, off, dinv);

    // ---- active set (staging dead; mark/cnt reuse it) ----
    hipMemsetAsync(mark, 0, (N_NODES + 1) * sizeof(int), stream);  // mark + acnt
    activeset_k<<<128, 256, 0, stream>>>(ed, off, mark, alist, acnt);

    // ---- layer 1 ----
    xs_k<<<(N_NODES * IN_F + 255) / 256, 256, 0, stream>>>(x, dinv, (bf16*)xs,
                                                           N_NODES * IN_F);
    gath32_dual_k<<<(N_NODES * 4 + 255) / 256, 256, 0, stream>>>(ed, off, dinv,
                                                                 (const uint4*)xs,
                                                                 (uint4*)p1, (uint4*)u1,
                                                                 N_NODES);
    gath32_one_k<<<(N_NODES * 4 + 255) / 256, 256, 0, stream>>>(ed, off, dinv,
                                                                (const uint4*)u1,
                                                                (uint4*)p2, N_NODES);
    dense1m_k<<<(N_NODES + 63) / 64, 256, 0, stream>>>(x, p1, p2, w1, b1, dinv,
                                                       (bf16*)h1s, h1p);

    // ---- layer 2: restricted to AP nodes + their in-neighbors ----
    gath64_q1_k<<<(NUM_APS * 32 + 255) / 256, 256, 0, stream>>>(ed, off, dinv, h1s,
                                                                u3, (unsigned*)q1,
                                                                NUM_APS);
    gath64_act_k<<<(LISTCAP * 32 + 255) / 256, 256, 0, stream>>>(ed, off, dinv, h1s,
                                                                 alist, acnt, u3);
    gath64_one_k<<<(NUM_APS * 32 + 255) / 256, 256, 0, stream>>>(ed, off, dinv, u3,
                                                                 (unsigned*)q2, NUM_APS);
    dense2_k<<<(NUM_APS + 3) / 4, 256, 0, stream>>>(h1p, q1, q2, w2, b2, ap);

    // ---- heads ----
    logits_k<<<(NUM_APS * 6 + 255) / 256, 256, 0, stream>>>(ap, wch, bch, wpw, bpw,
                                                            (float*)d_out);
}

// Round 17
// 183.022 us; speedup vs baseline: 1.1125x; 1.1125x over previous
//
#include <hip/hip_runtime.h>
#include <hip/hip_bf16.h>

#define N_NODES 100000
#define NUM_APS 1000
#define IN_F 32
#define HID 64
#define NB 391      // bins of 256 cols: 391*256 = 100096 >= N_NODES
#define EBLK 4096   // edges per chunk (keeps ~10.5-record bin tails -> merged writes)
#define NGRP 4      // bin-groups per chunk (grid x4 for occupancy)
#define GRPSZ 98    // ceil(NB/NGRP)
#define CAPB 4608   // per-bin staging capacity (mean 4092, +8 sigma), guarded
#define LISTCAP 24000

typedef __hip_bfloat16 bf16;
typedef unsigned long long ull;
typedef __attribute__((ext_vector_type(8))) short bf16x8;
typedef __attribute__((ext_vector_type(4))) float f32x4;

__device__ __forceinline__ float b2f(bf16 v) { return __bfloat162float(v); }
__device__ __forceinline__ float blo(unsigned u) { return __uint_as_float(u << 16); }
__device__ __forceinline__ float bhi(unsigned u) { return __uint_as_float(u & 0xffff0000u); }
__device__ __forceinline__ unsigned packbf(float x, float y) {
    bf16 a = __float2bfloat16(x), b = __float2bfloat16(y);
    unsigned short ua = *reinterpret_cast<unsigned short*>(&a);
    unsigned short ub = *reinterpret_cast<unsigned short*>(&b);
    return (unsigned)ua | ((unsigned)ub << 16);
}
__device__ __forceinline__ short f2bs(float v) {
    bf16 t = __float2bfloat16(v);
    return *reinterpret_cast<short*>(&t);
}
// 4B edge record: r<<15 | q15(ew)
__device__ __forceinline__ unsigned rec_r(unsigned v) { return v >> 15; }
__device__ __forceinline__ float rec_w(unsigned v) { return (v & 32767u) * (1.f / 32768.f); }

// ---------- binned CSR build, hist-free, bin-group partitioned ----------
// Each 4096-edge chunk is handled by NGRP=4 blocks; block g owns bins
// [g*GRPSZ,(g+1)*GRPSZ). Merge length per (block,bin) tail stays ~10.5 records
// while grid is 4x larger (1564 blocks) for latency hiding.
__global__ __launch_bounds__(256) void binwrite3_k(const int* __restrict__ row,
                                                   const int* __restrict__ col,
                                                   const float* __restrict__ ew,
                                                   int* __restrict__ binPtr,
                                                   ull* __restrict__ staging, int E) {
    __shared__ int h1[GRPSZ];
    __shared__ int base[GRPSZ];
    __shared__ int h2[GRPSZ];
    int g = blockIdx.x & (NGRP - 1);
    int eb = blockIdx.x >> 2;
    for (int i = threadIdx.x; i < GRPSZ; i += 256) { h1[i] = 0; h2[i] = 0; }
    __syncthreads();
    int e0 = eb * EBLK, e1 = min(e0 + EBLK, E);
    int bmin = g * GRPSZ, bmax = bmin + GRPSZ;
    for (int e = e0 + threadIdx.x; e < e1; e += 256) {
        int b = col[e] >> 8;
        if (b >= bmin && b < bmax) atomicAdd(&h1[b - bmin], 1);
    }
    __syncthreads();
    for (int i = threadIdx.x; i < GRPSZ; i += 256) {
        int v = h1[i];
        base[i] = v ? atomicAdd(&binPtr[bmin + i], v) : 0;
    }
    __syncthreads();
    for (int e = e0 + threadIdx.x; e < e1; e += 256) {
        int c = col[e];
        int b = c >> 8;
        if (b < bmin || b >= bmax) continue;
        int slot = atomicAdd(&h2[b - bmin], 1);
        unsigned q = (unsigned)(ew[e] * 32768.0f + 0.5f);
        if (q > 32767u) q = 32767u;
        ull rec = ((ull)(unsigned)(c & 255) << 32) |
                  (ull)(((unsigned)row[e] << 15) | q);
        int pos = base[b - bmin] + slot;
        if (pos < CAPB) staging[(size_t)b * CAPB + pos] = rec;
    }
}

__global__ __launch_bounds__(512) void binscan2_k(const int* __restrict__ binPtr,
                                                  int* __restrict__ binBase) {
    __shared__ int s[512];
    int v = (threadIdx.x < NB) ? min(binPtr[threadIdx.x], CAPB) : 0;
    s[threadIdx.x] = v;
    __syncthreads();
    for (int d = 1; d < 512; d <<= 1) {
        int t = (threadIdx.x >= d) ? s[threadIdx.x - d] : 0;
        __syncthreads();
        s[threadIdx.x] += t;
        __syncthreads();
    }
    if (threadIdx.x <= NB) binBase[threadIdx.x] = s[threadIdx.x] - v;
}

__global__ __launch_bounds__(256) void binfin2_k(const ull* __restrict__ staging,
                                                 const int* __restrict__ binBase,
                                                 unsigned* __restrict__ ed,
                                                 int* __restrict__ off,
                                                 float* __restrict__ dinv) {
    __shared__ unsigned cnt[256];
    __shared__ unsigned degq[256];
    __shared__ int wptr[256];
    __shared__ unsigned s[256];
    int b = blockIdx.x;
    int e0 = binBase[b];
    int cntb = binBase[b + 1] - e0;
    const ull* st = staging + (size_t)b * CAPB;
    cnt[threadIdx.x] = 0;
    degq[threadIdx.x] = 0;
    __syncthreads();
    for (int i = threadIdx.x; i < cntb; i += 256) {
        ull rec = st[i];
        unsigned cl = (unsigned)(rec >> 32) & 255u;
        atomicAdd(&cnt[cl], 1u);
        atomicAdd(&degq[cl], (unsigned)rec & 32767u);
    }
    __syncthreads();
    unsigned v = cnt[threadIdx.x];
    s[threadIdx.x] = v;
    __syncthreads();
    for (int d = 1; d < 256; d <<= 1) {
        unsigned t = (threadIdx.x >= d) ? s[threadIdx.x - d] : 0;
        __syncthreads();
        s[threadIdx.x] += t;
        __syncthreads();
    }
    int colg = (b << 8) + threadIdx.x;
    if (colg < N_NODES) {
        off[colg] = e0 + (int)s[threadIdx.x];  // segment END
        float deg = (float)degq[threadIdx.x] * (1.0f / 32768.0f);
        dinv[colg] = deg > 0.f ? 1.0f / sqrtf(deg) : 0.f;
    }
    wptr[threadIdx.x] = e0 + (int)s[threadIdx.x] - (int)v;  // exclusive start
    __syncthreads();
    for (int i = threadIdx.x; i < cntb; i += 256) {
        ull rec = st[i];
        unsigned cl = (unsigned)(rec >> 32) & 255u;
        int pos = atomicAdd(&wptr[cl], 1);
        ed[pos] = (unsigned)rec;  // low 32 bits = r<<15 | q15
    }
}

// ---------- active set (verbatim) ----------
__global__ __launch_bounds__(256) void activeset_k(const unsigned* __restrict__ ed,
                                                   const int* __restrict__ off,
                                                   int* __restrict__ mark,
                                                   int* __restrict__ list,
                                                   int* __restrict__ cnt) {
    int e = blockIdx.x * 256 + threadIdx.x;
    int end = off[NUM_APS - 1];
    if (e >= end) return;
    int r = (int)rec_r(ed[e]);
    if (atomicExch(&mark[r], 1) == 0) {
        int pos = atomicAdd(cnt, 1);
        if (pos < LISTCAP) list[pos] = r;
    }
}

// xs = dinv ⊙ x, to bf16  (verbatim)
__global__ void xs_k(const float* __restrict__ x, const float* __restrict__ dinv,
                     bf16* __restrict__ xb, int n) {
    int i = blockIdx.x * blockDim.x + threadIdx.x;
    if (i >= n) return;
    xb[i] = __float2bfloat16(x[i] * dinv[i >> 5]);
}

// ---------- 32-feat gathers: 4 lanes/node, uint4 loads (verbatim round 14) ----------
__global__ __launch_bounds__(256) void gath32_dual_k(const unsigned* __restrict__ ed,
                                                     const int* __restrict__ off,
                                                     const float* __restrict__ dinv,
                                                     const uint4* __restrict__ src4,
                                                     uint4* __restrict__ p4,
                                                     uint4* __restrict__ u4, int nn) {
    int t = blockIdx.x * 256 + threadIdx.x;
    int n = t >> 2;
    if (n >= nn) return;
    int qd = t & 3;
    int s = (n == 0) ? 0 : off[n - 1];
    int e = off[n];
    float aA[8] = {0,0,0,0,0,0,0,0};
    float aB[8] = {0,0,0,0,0,0,0,0};
    float aC[8] = {0,0,0,0,0,0,0,0};
    float aD[8] = {0,0,0,0,0,0,0,0};
    int i = s;
    for (; i + 4 <= e; i += 4) {
        unsigned v0 = ed[i], v1 = ed[i + 1], v2 = ed[i + 2], v3 = ed[i + 3];
        uint4 s0 = src4[rec_r(v0) * 4 + qd];
        uint4 s1 = src4[rec_r(v1) * 4 + qd];
        uint4 s2 = src4[rec_r(v2) * 4 + qd];
        uint4 s3 = src4[rec_r(v3) * 4 + qd];
        float w0 = rec_w(v0), w1 = rec_w(v1), w2 = rec_w(v2), w3 = rec_w(v3);
        aA[0] += w0 * blo(s0.x); aA[1] += w0 * bhi(s0.x);
        aA[2] += w0 * blo(s0.y); aA[3] += w0 * bhi(s0.y);
        aA[4] += w0 * blo(s0.z); aA[5] += w0 * bhi(s0.z);
        aA[6] += w0 * blo(s0.w); aA[7] += w0 * bhi(s0.w);
        aB[0] += w1 * blo(s1.x); aB[1] += w1 * bhi(s1.x);
        aB[2] += w1 * blo(s1.y); aB[3] += w1 * bhi(s1.y);
        aB[4] += w1 * blo(s1.z); aB[5] += w1 * bhi(s1.z);
        aB[6] += w1 * blo(s1.w); aB[7] += w1 * bhi(s1.w);
        aC[0] += w2 * blo(s2.x); aC[1] += w2 * bhi(s2.x);
        aC[2] += w2 * blo(s2.y); aC[3] += w2 * bhi(s2.y);
        aC[4] += w2 * blo(s2.z); aC[5] += w2 * bhi(s2.z);
        aC[6] += w2 * blo(s2.w); aC[7] += w2 * bhi(s2.w);
        aD[0] += w3 * blo(s3.x); aD[1] += w3 * bhi(s3.x);
        aD[2] += w3 * blo(s3.y); aD[3] += w3 * bhi(s3.y);
        aD[4] += w3 * blo(s3.z); aD[5] += w3 * bhi(s3.z);
        aD[6] += w3 * blo(s3.w); aD[7] += w3 * bhi(s3.w);
    }
    for (; i < e; ++i) {
        unsigned v = ed[i];
        uint4 sv = src4[rec_r(v) * 4 + qd];
        float w = rec_w(v);
        aA[0] += w * blo(sv.x); aA[1] += w * bhi(sv.x);
        aA[2] += w * blo(sv.y); aA[3] += w * bhi(sv.y);
        aA[4] += w * blo(sv.z); aA[5] += w * bhi(sv.z);
        aA[6] += w * blo(sv.w); aA[7] += w * bhi(sv.w);
    }
#pragma unroll
    for (int k = 0; k < 8; ++k) aA[k] += aB[k] + aC[k] + aD[k];
    float d = dinv[n], d2 = d * d;
    p4[n * 4 + qd] = make_uint4(packbf(d * aA[0], d * aA[1]), packbf(d * aA[2], d * aA[3]),
                                packbf(d * aA[4], d * aA[5]), packbf(d * aA[6], d * aA[7]));
    u4[n * 4 + qd] = make_uint4(packbf(d2 * aA[0], d2 * aA[1]), packbf(d2 * aA[2], d2 * aA[3]),
                                packbf(d2 * aA[4], d2 * aA[5]), packbf(d2 * aA[6], d2 * aA[7]));
}

__global__ __launch_bounds__(256) void gath32_one_k(const unsigned* __restrict__ ed,
                                                    const int* __restrict__ off,
                                                    const float* __restrict__ dinv,
                                                    const uint4* __restrict__ src4,
                                                    uint4* __restrict__ p4, int nn) {
    int t = blockIdx.x * 256 + threadIdx.x;
    int n = t >> 2;
    if (n >= nn) return;
    int qd = t & 3;
    int s = (n == 0) ? 0 : off[n - 1];
    int e = off[n];
    float aA[8] = {0,0,0,0,0,0,0,0};
    float aB[8] = {0,0,0,0,0,0,0,0};
    float aC[8] = {0,0,0,0,0,0,0,0};
    float aD[8] = {0,0,0,0,0,0,0,0};
    int i = s;
    for (; i + 4 <= e; i += 4) {
        unsigned v0 = ed[i], v1 = ed[i + 1], v2 = ed[i + 2], v3 = ed[i + 3];
        uint4 s0 = src4[rec_r(v0) * 4 + qd];
        uint4 s1 = src4[rec_r(v1) * 4 + qd];
        uint4 s2 = src4[rec_r(v2) * 4 + qd];
        uint4 s3 = src4[rec_r(v3) * 4 + qd];
        float w0 = rec_w(v0), w1 = rec_w(v1), w2 = rec_w(v2), w3 = rec_w(v3);
        aA[0] += w0 * blo(s0.x); aA[1] += w0 * bhi(s0.x);
        aA[2] += w0 * blo(s0.y); aA[3] += w0 * bhi(s0.y);
        aA[4] += w0 * blo(s0.z); aA[5] += w0 * bhi(s0.z);
        aA[6] += w0 * blo(s0.w); aA[7] += w0 * bhi(s0.w);
        aB[0] += w1 * blo(s1.x); aB[1] += w1 * bhi(s1.x);
        aB[2] += w1 * blo(s1.y); aB[3] += w1 * bhi(s1.y);
        aB[4] += w1 * blo(s1.z); aB[5] += w1 * bhi(s1.z);
        aB[6] += w1 * blo(s1.w); aB[7] += w1 * bhi(s1.w);
        aC[0] += w2 * blo(s2.x); aC[1] += w2 * bhi(s2.x);
        aC[2] += w2 * blo(s2.y); aC[3] += w2 * bhi(s2.y);
        aC[4] += w2 * blo(s2.z); aC[5] += w2 * bhi(s2.z);
        aC[6] += w2 * blo(s2.w); aC[7] += w2 * bhi(s2.w);
        aD[0] += w3 * blo(s3.x); aD[1] += w3 * bhi(s3.x);
        aD[2] += w3 * blo(s3.y); aD[3] += w3 * bhi(s3.y);
        aD[4] += w3 * blo(s3.z); aD[5] += w3 * bhi(s3.z);
        aD[6] += w3 * blo(s3.w); aD[7] += w3 * bhi(s3.w);
    }
    for (; i < e; ++i) {
        unsigned v = ed[i];
        uint4 sv = src4[rec_r(v) * 4 + qd];
        float w = rec_w(v);
        aA[0] += w * blo(sv.x); aA[1] += w * bhi(sv.x);
        aA[2] += w * blo(sv.y); aA[3] += w * bhi(sv.y);
        aA[4] += w * blo(sv.z); aA[5] += w * bhi(sv.z);
        aA[6] += w * blo(sv.w); aA[7] += w * bhi(sv.w);
    }
#pragma unroll
    for (int k = 0; k < 8; ++k) aA[k] += aB[k] + aC[k] + aD[k];
    float d = dinv[n];
    p4[n * 4 + qd] = make_uint4(packbf(d * aA[0], d * aA[1]), packbf(d * aA[2], d * aA[3]),
                                packbf(d * aA[4], d * aA[5]), packbf(d * aA[6], d * aA[7]));
}

// ---------- 64-feat gathers (verbatim, pruned domain) ----------
__global__ __launch_bounds__(256) void gath64_q1_k(const unsigned* __restrict__ ed,
                                                   const int* __restrict__ off,
                                                   const float* __restrict__ dinv,
                                                   const unsigned* __restrict__ src,
                                                   unsigned* __restrict__ u,
                                                   unsigned* __restrict__ q, int nn) {
    int t = blockIdx.x * 256 + threadIdx.x;
    int n = t >> 5;
    if (n >= nn) return;
    int fp = t & 31;
    int s = (n == 0) ? 0 : off[n - 1];
    int e = off[n];
    float a0 = 0.f, a1 = 0.f, b0 = 0.f, b1 = 0.f;
    int i = s;
    for (; i + 4 <= e; i += 4) {
        unsigned v0 = ed[i], v1 = ed[i + 1], v2 = ed[i + 2], v3 = ed[i + 3];
        unsigned s0 = src[rec_r(v0) * 32 + fp];
        unsigned s1 = src[rec_r(v1) * 32 + fp];
        unsigned s2 = src[rec_r(v2) * 32 + fp];
        unsigned s3 = src[rec_r(v3) * 32 + fp];
        float w0 = rec_w(v0), w1 = rec_w(v1), w2 = rec_w(v2), w3 = rec_w(v3);
        a0 += w0 * blo(s0); a1 += w0 * bhi(s0);
        b0 += w1 * blo(s1); b1 += w1 * bhi(s1);
        a0 += w2 * blo(s2); a1 += w2 * bhi(s2);
        b0 += w3 * blo(s3); b1 += w3 * bhi(s3);
    }
    for (; i < e; ++i) {
        unsigned v = ed[i];
        unsigned sv = src[rec_r(v) * 32 + fp];
        float w = rec_w(v);
        a0 += w * blo(sv); a1 += w * bhi(sv);
    }
    a0 += b0; a1 += b1;
    float d = dinv[n], d2 = d * d;
    u[n * 32 + fp] = packbf(d2 * a0, d2 * a1);
    q[n * 32 + fp] = packbf(d * a0, d * a1);
}

__global__ __launch_bounds__(256) void gath64_act_k(const unsigned* __restrict__ ed,
                                                    const int* __restrict__ off,
                                                    const float* __restrict__ dinv,
                                                    const unsigned* __restrict__ src,
                                                    const int* __restrict__ list,
                                                    const int* __restrict__ cnt,
                                                    unsigned* __restrict__ u) {
    int t = blockIdx.x * 256 + threadIdx.x;
    int idx = t >> 5;
    int c = *cnt;
    if (c > LISTCAP) c = LISTCAP;
    if (idx >= c) return;
    int n = list[idx];
    int fp = t & 31;
    int s = (n == 0) ? 0 : off[n - 1];
    int e = off[n];
    float a0 = 0.f, a1 = 0.f, b0 = 0.f, b1 = 0.f;
    int i = s;
    for (; i + 4 <= e; i += 4) {
        unsigned v0 = ed[i], v1 = ed[i + 1], v2 = ed[i + 2], v3 = ed[i + 3];
        unsigned s0 = src[rec_r(v0) * 32 + fp];
        unsigned s1 = src[rec_r(v1) * 32 + fp];
        unsigned s2 = src[rec_r(v2) * 32 + fp];
        unsigned s3 = src[rec_r(v3) * 32 + fp];
        float w0 = rec_w(v0), w1 = rec_w(v1), w2 = rec_w(v2), w3 = rec_w(v3);
        a0 += w0 * blo(s0); a1 += w0 * bhi(s0);
        b0 += w1 * blo(s1); b1 += w1 * bhi(s1);
        a0 += w2 * blo(s2); a1 += w2 * bhi(s2);
        b0 += w3 * blo(s3); b1 += w3 * bhi(s3);
    }
    for (; i < e; ++i) {
        unsigned v = ed[i];
        unsigned sv = src[rec_r(v) * 32 + fp];
        float w = rec_w(v);
        a0 += w * blo(sv); a1 += w * bhi(sv);
    }
    a0 += b0; a1 += b1;
    float d = dinv[n], d2 = d * d;
    u[n * 32 + fp] = packbf(d2 * a0, d2 * a1);
}

__global__ __launch_bounds__(256) void gath64_one_k(const unsigned* __restrict__ ed,
                                                    const int* __restrict__ off,
                                                    const float* __restrict__ dinv,
                                                    const unsigned* __restrict__ src,
                                                    unsigned* __restrict__ q, int nn) {
    int t = blockIdx.x * 256 + threadIdx.x;
    int n = t >> 5;
    if (n >= nn) return;
    int fp = t & 31;
    int s = (n == 0) ? 0 : off[n - 1];
    int e = off[n];
    float a0 = 0.f, a1 = 0.f, b0 = 0.f, b1 = 0.f;
    int i = s;
    for (; i + 4 <= e; i += 4) {
        unsigned v0 = ed[i], v1 = ed[i + 1], v2 = ed[i + 2], v3 = ed[i + 3];
        unsigned s0 = src[rec_r(v0) * 32 + fp];
        unsigned s1 = src[rec_r(v1) * 32 + fp];
        unsigned s2 = src[rec_r(v2) * 32 + fp];
        unsigned s3 = src[rec_r(v3) * 32 + fp];
        float w0 = rec_w(v0), w1 = rec_w(v1), w2 = rec_w(v2), w3 = rec_w(v3);
        a0 += w0 * blo(s0); a1 += w0 * bhi(s0);
        b0 += w1 * blo(s1); b1 += w1 * bhi(s1);
        a0 += w2 * blo(s2); a1 += w2 * bhi(s2);
        b0 += w3 * blo(s3); b1 += w3 * bhi(s3);
    }
    for (; i < e; ++i) {
        unsigned v = ed[i];
        unsigned sv = src[rec_r(v) * 32 + fp];
        float w = rec_w(v);
        a0 += w * blo(sv); a1 += w * bhi(sv);
    }
    a0 += b0; a1 += b1;
    float d = dinv[n];
    q[n * 32 + fp] = packbf(d * a0, d * a1);
}

// ---------- dense layer 1 on MFMA (verbatim round 15, verified) ----------
__global__ __launch_bounds__(256) void dense1m_k(const float* __restrict__ x,
                                                 const unsigned* __restrict__ p1,
                                                 const unsigned* __restrict__ p2,
                                                 const float* __restrict__ w,
                                                 const float* __restrict__ b,
                                                 const float* __restrict__ dinv,
                                                 bf16* __restrict__ h1s,
                                                 bf16* __restrict__ h1p) {
    __shared__ short sxb[64 * 104];   // inputs bf16 [node][k], 13.3 KB
    __shared__ short swt[64 * 104];   // weights^T bf16 [col][k], 13.3 KB
    __shared__ float sbias[64];
    __shared__ float sdv[64];
    int tid = threadIdx.x;
    int nb = blockIdx.x * 64;
    for (int idx = tid; idx < 96 * 64; idx += 256) {
        int j = idx >> 6, f = idx & 63;
        swt[f * 104 + j] = f2bs(w[idx]);
    }
    for (int i = tid; i < 64 * 16; i += 256) {
        int n = i >> 4, c = i & 15;
        int gn = nb + n;
        float v0 = 0.f, v1 = 0.f;
        if (gn < N_NODES) {
            v0 = x[(size_t)gn * 32 + 2 * c];
            v1 = x[(size_t)gn * 32 + 2 * c + 1];
        }
        ((unsigned*)sxb)[n * 52 + c] = packbf(v0, v1);
    }
    for (int i = tid; i < 64 * 16; i += 256) {
        int n = i >> 4, c = i & 15;
        int gn = nb + n;
        unsigned v1 = 0u, v2 = 0u;
        if (gn < N_NODES) {
            v1 = p1[(size_t)gn * 16 + c];
            v2 = p2[(size_t)gn * 16 + c];
        }
        ((unsigned*)sxb)[n * 52 + 16 + c] = v1;
        ((unsigned*)sxb)[n * 52 + 32 + c] = v2;
    }
    if (tid < 64) {
        sbias[tid] = b[tid];
        int gn = nb + tid;
        sdv[tid] = (gn < N_NODES) ? dinv[gn] : 0.f;
    }
    __syncthreads();

    int lane = tid & 63;
    int wt = tid >> 6;
    int lr = lane & 15;
    int kg = lane >> 4;
    const short* arow = &sxb[(wt * 16 + lr) * 104 + kg * 8];
    bf16x8 a0 = *(const bf16x8*)(arow);
    bf16x8 a1 = *(const bf16x8*)(arow + 32);
    bf16x8 a2 = *(const bf16x8*)(arow + 64);
#pragma unroll
    for (int ct = 0; ct < 4; ++ct) {
        const short* bcol = &swt[(ct * 16 + lr) * 104 + kg * 8];
        bf16x8 b0 = *(const bf16x8*)(bcol);
        bf16x8 b1 = *(const bf16x8*)(bcol + 32);
        bf16x8 b2 = *(const bf16x8*)(bcol + 64);
        f32x4 acc = {0.f, 0.f, 0.f, 0.f};
        acc = __builtin_amdgcn_mfma_f32_16x16x32_bf16(a0, b0, acc, 0, 0, 0);
        acc = __builtin_amdgcn_mfma_f32_16x16x32_bf16(a1, b1, acc, 0, 0, 0);
        acc = __builtin_amdgcn_mfma_f32_16x16x32_bf16(a2, b2, acc, 0, 0, 0);
        int colo = ct * 16 + lr;
        float bias = sbias[colo];
#pragma unroll
        for (int r = 0; r < 4; ++r) {
            int rowl = wt * 16 + kg * 4 + r;
            int gn = nb + rowl;
            if (gn < N_NODES) {
                float a = acc[r] + bias;
                a = a > 0.f ? a : 0.01f * a;
                h1s[(size_t)gn * HID + colo] = __float2bfloat16(a * sdv[rowl]);
                if (gn < NUM_APS) h1p[(size_t)gn * HID + colo] = __float2bfloat16(a);
            }
        }
    }
}

// dense2 (verbatim)
__global__ __launch_bounds__(256) void dense2_k(const bf16* __restrict__ h1p,
                                                const bf16* __restrict__ q1,
                                                const bf16* __restrict__ q2,
                                                const float* __restrict__ w,
                                                const float* __restrict__ b,
                                                float* __restrict__ ap) {
    __shared__ float sw[3 * HID * HID];  // 48 KB
    __shared__ float sx[4][3 * HID];
    for (int i = threadIdx.x; i < 3 * HID * HID; i += 256) sw[i] = w[i];
    int nb = blockIdx.x * 4;
    for (int k = threadIdx.x; k < 4 * 192; k += 256) {
        int ln = k / 192, j = k % 192;
        int n = nb + ln;
        float v = 0.f;
        if (n < NUM_APS) {
            int hop = j >> 6, ii = j & 63;
            const bf16* sp = (hop == 0) ? h1p : (hop == 1 ? q1 : q2);
            v = b2f(sp[n * HID + ii]);
        }
        sx[ln][j] = v;
    }
    __syncthreads();
    int ln = threadIdx.x >> 6;
    int n = nb + ln;
    if (n >= NUM_APS) return;
    int f = threadIdx.x & 63;
    float acc = b[f];
#pragma unroll 8
    for (int j = 0; j < 192; ++j) acc += sx[ln][j] * sw[j * HID + f];
    acc = acc > 0.f ? acc : 0.01f * acc;
    ap[n * HID + f] = acc;
}

// two 64->3 heads (verbatim)
__global__ void logits_k(const float* __restrict__ ap,
                         const float* __restrict__ wch, const float* __restrict__ bch,
                         const float* __restrict__ wpw, const float* __restrict__ bpw,
                         float* __restrict__ out) {
    int idx = blockIdx.x * blockDim.x + threadIdx.x;
    if (idx >= NUM_APS * 6) return;
    int n = idx / 6, j = idx % 6;
    const float* w;
    float bb;
    float* o;
    if (j < 3) {
        w = wch + j; bb = bch[j]; o = out + n * 3 + j;
    } else {
        int jj = j - 3;
        w = wpw + jj; bb = bpw[jj]; o = out + NUM_APS * 3 + n * 3 + jj;
    }
    float acc = bb;
    const float* a = ap + n * HID;
#pragma unroll
    for (int i = 0; i < HID; ++i) acc += a[i] * w[i * 3];
    *o = acc;
}

extern "C" void kernel_launch(void* const* d_in, const int* in_sizes, int n_in,
                              void* d_out, int out_size, void* d_ws, size_t ws_size,
                              hipStream_t stream) {
    const float* x   = (const float*)d_in[0];
    const int*   ei  = (const int*)d_in[1];
    const float* ea  = (const float*)d_in[2];
    const float* w1  = (const float*)d_in[3];
    const float* b1  = (const float*)d_in[4];
    const float* w2  = (const float*)d_in[5];
    const float* b2  = (const float*)d_in[6];
    const float* wch = (const float*)d_in[7];
    const float* bch = (const float*)d_in[8];
    const float* wpw = (const float*)d_in[9];
    const float* bpw = (const float*)d_in[10];

    const int E = in_sizes[2];  // 1,600,000
    const int* row  = ei;
    const int* colv = ei + E;

    // ---- workspace layout (4-byte units), ~48.2 MB (verbatim round 15) ----
    float* ws = (float*)d_ws;
    ull*      staging = (ull*)ws;                     // [0, 3,603,456)
    int*      mark    = (int*)ws;                     // 100,000 ints (overlays staging)
    int*      acnt    = (int*)(ws + 100000);          // 1 int
    int*      alist   = (int*)(ws + 100001);          // LISTCAP ints
    unsigned* ed      = (unsigned*)(ws + 3700000);    // [3.7M, 5.3M)
    int*      binPtr  = (int*)(ws + 5300000);         // 512
    int*      binBase = (int*)(ws + 5300512);         // 512 (needs NB+1)
    int*      off     = (int*)(ws + 5301024);         // +100,000
    float*    dinv    = ws + 5401024;                 // +100,000
    unsigned* xs      = (unsigned*)(ws + 5501024);    // 1.6M (16B-aligned)
    unsigned* u1      = xs + 1600000;                 // 1.6M
    unsigned* p1      = (unsigned*)(ws + 8701024);    // 1.6M
    unsigned* p2      = p1 + 1600000;                 // 1.6M
    unsigned* h1s     = xs;                           // overlays xs∪u1 (3.2M)
    unsigned* u3      = p1;                           // overlays p1∪p2 (3.2M)
    bf16*     h1p     = (bf16*)(ws + 11901024);       // 32K units
    bf16*     q1      = (bf16*)(ws + 11933024);       // 32K
    bf16*     q2      = (bf16*)(ws + 11965024);       // 32K
    float*    ap      = ws + 11997024;                // 64K

    const int gridE = (E + EBLK - 1) / EBLK;  // 391 chunks

    // ---- hist-free binned CSR build (bin-group partitioned) ----
    hipMemsetAsync(binPtr, 0, 512 * sizeof(int), stream);
    binwrite3_k<<<gridE * NGRP, 256, 0, stream>>>(row, colv, ea, binPtr, staging, E);
    binscan2_k<<<1, 512, 0, stream>>>(binPtr, binBase);
    binfin2_k<<<NB, 256, 0, stream>>>(staging, binBase, ed, off, dinv);

    // ---- active set (staging dead; mark/cnt reuse it) ----
    hipMemsetAsync(mark, 0, (N_NODES + 1) * sizeof(int), stream);  // mark + acnt
    activeset_k<<<128, 256, 0, stream>>>(ed, off, mark, alist, acnt);

    // ---- layer 1 ----
    xs_k<<<(N_NODES * IN_F + 255) / 256, 256, 0, stream>>>(x, dinv, (bf16*)xs,
                                                           N_NODES * IN_F);
    gath32_dual_k<<<(N_NODES * 4 + 255) / 256, 256, 0, stream>>>(ed, off, dinv,
                                                                 (const uint4*)xs,
                                                                 (uint4*)p1, (uint4*)u1,
                                                                 N_NODES);
    gath32_one_k<<<(N_NODES * 4 + 255) / 256, 256, 0, stream>>>(ed, off, dinv,
                                                                (const uint4*)u1,
                                                                (uint4*)p2, N_NODES);
    dense1m_k<<<(N_NODES + 63) / 64, 256, 0, stream>>>(x, p1, p2, w1, b1, dinv,
                                                       (bf16*)h1s, h1p);

    // ---- layer 2: restricted to AP nodes + their in-neighbors ----
    gath64_q1_k<<<(NUM_APS * 32 + 255) / 256, 256, 0, stream>>>(ed, off, dinv, h1s,
                                                                u3, (unsigned*)q1,
                                                                NUM_APS);
    gath64_act_k<<<(LISTCAP * 32 + 255) / 256, 256, 0, stream>>>(ed, off, dinv, h1s,
                                                                 alist, acnt, u3);
    gath64_one_k<<<(NUM_APS * 32 + 255) / 256, 256, 0, stream>>>(ed, off, dinv, u3,
                                                                 (unsigned*)q2, NUM_APS);
    dense2_k<<<(NUM_APS + 3) / 4, 256, 0, stream>>>(h1p, q1, q2, w2, b2, ap);

    // ---- heads ----
    logits_k<<<(NUM_APS * 6 + 255) / 256, 256, 0, stream>>>(ap, wch, bch, wpw, bpw,
                                                            (float*)d_out);
}

// Round 18
// 159.525 us; speedup vs baseline: 1.2764x; 1.1473x over previous
//
#include <hip/hip_runtime.h>
#include <hip/hip_bf16.h>

#define N_NODES 100000
#define NUM_APS 1000
#define IN_F 32
#define HID 64
#define NB 391      // bins of 256 cols: 391*256 = 100096 >= N_NODES
#define EPB 4096    // edges per block (keeps ~10.5-record bin tails -> merged writes)
#define CAPB 4608   // per-bin staging capacity (mean 4092, +8 sigma), guarded
#define LISTCAP 24000

typedef __hip_bfloat16 bf16;
typedef unsigned long long ull;
typedef __attribute__((ext_vector_type(8))) short bf16x8;
typedef __attribute__((ext_vector_type(4))) float f32x4;

__device__ __forceinline__ float b2f(bf16 v) { return __bfloat162float(v); }
__device__ __forceinline__ float blo(unsigned u) { return __uint_as_float(u << 16); }
__device__ __forceinline__ float bhi(unsigned u) { return __uint_as_float(u & 0xffff0000u); }
__device__ __forceinline__ unsigned packbf(float x, float y) {
    bf16 a = __float2bfloat16(x), b = __float2bfloat16(y);
    unsigned short ua = *reinterpret_cast<unsigned short*>(&a);
    unsigned short ub = *reinterpret_cast<unsigned short*>(&b);
    return (unsigned)ua | ((unsigned)ub << 16);
}
__device__ __forceinline__ short f2bs(float v) {
    bf16 t = __float2bfloat16(v);
    return *reinterpret_cast<short*>(&t);
}
// 4B edge record: r<<15 | q15(ew)
__device__ __forceinline__ unsigned rec_r(unsigned v) { return v >> 15; }
__device__ __forceinline__ float rec_w(unsigned v) { return (v & 32767u) * (1.f / 32768.f); }

// ---------- binned CSR build, hist-free ----------
// 512 threads: each thread walks 8 edges/phase (was 16) and waves/CU doubles
// (6 -> 12) at identical total scan work and identical ~10.5-record merge tails.
__global__ __launch_bounds__(512) void binwrite2_k(const int* __restrict__ row,
                                                   const int* __restrict__ col,
                                                   const float* __restrict__ ew,
                                                   int* __restrict__ binPtr,
                                                   ull* __restrict__ staging, int E) {
    __shared__ int h1[NB];
    __shared__ int base[NB];
    __shared__ int h2[NB];
    for (int i = threadIdx.x; i < NB; i += 512) { h1[i] = 0; h2[i] = 0; }
    __syncthreads();
    int e0 = blockIdx.x * EPB, e1 = min(e0 + EPB, E);
    for (int e = e0 + threadIdx.x; e < e1; e += 512) atomicAdd(&h1[col[e] >> 8], 1);
    __syncthreads();
    for (int i = threadIdx.x; i < NB; i += 512) {
        int v = h1[i];
        base[i] = v ? atomicAdd(&binPtr[i], v) : 0;
    }
    __syncthreads();
    for (int e = e0 + threadIdx.x; e < e1; e += 512) {
        int c = col[e];
        int b = c >> 8;
        int slot = atomicAdd(&h2[b], 1);
        unsigned q = (unsigned)(ew[e] * 32768.0f + 0.5f);
        if (q > 32767u) q = 32767u;
        ull rec = ((ull)(unsigned)(c & 255) << 32) |
                  (ull)(((unsigned)row[e] << 15) | q);
        int pos = base[b] + slot;
        if (pos < CAPB) staging[(size_t)b * CAPB + pos] = rec;
    }
}

__global__ __launch_bounds__(512) void binscan2_k(const int* __restrict__ binPtr,
                                                  int* __restrict__ binBase) {
    __shared__ int s[512];
    int v = (threadIdx.x < NB) ? min(binPtr[threadIdx.x], CAPB) : 0;
    s[threadIdx.x] = v;
    __syncthreads();
    for (int d = 1; d < 512; d <<= 1) {
        int t = (threadIdx.x >= d) ? s[threadIdx.x - d] : 0;
        __syncthreads();
        s[threadIdx.x] += t;
        __syncthreads();
    }
    if (threadIdx.x <= NB) binBase[threadIdx.x] = s[threadIdx.x] - v;
}

// binfin2x: bin sort + off/dinv AND fused xs = dinv ⊙ x (block b owns nodes
// [b*256,(b+1)*256) -- exactly the cols whose dinv it just computed).
__global__ __launch_bounds__(256) void binfin2x_k(const ull* __restrict__ staging,
                                                  const int* __restrict__ binBase,
                                                  const float* __restrict__ x,
                                                  unsigned* __restrict__ ed,
                                                  int* __restrict__ off,
                                                  float* __restrict__ dinv,
                                                  unsigned* __restrict__ xs) {
    __shared__ unsigned cnt[256];
    __shared__ unsigned degq[256];
    __shared__ int wptr[256];
    __shared__ unsigned s[256];
    __shared__ float sdv[256];
    int b = blockIdx.x;
    int e0 = binBase[b];
    int cntb = binBase[b + 1] - e0;
    const ull* st = staging + (size_t)b * CAPB;
    cnt[threadIdx.x] = 0;
    degq[threadIdx.x] = 0;
    __syncthreads();
    for (int i = threadIdx.x; i < cntb; i += 256) {
        ull rec = st[i];
        unsigned cl = (unsigned)(rec >> 32) & 255u;
        atomicAdd(&cnt[cl], 1u);
        atomicAdd(&degq[cl], (unsigned)rec & 32767u);
    }
    __syncthreads();
    unsigned v = cnt[threadIdx.x];
    s[threadIdx.x] = v;
    __syncthreads();
    for (int d = 1; d < 256; d <<= 1) {
        unsigned t = (threadIdx.x >= d) ? s[threadIdx.x - d] : 0;
        __syncthreads();
        s[threadIdx.x] += t;
        __syncthreads();
    }
    int colg = (b << 8) + threadIdx.x;
    float dv = 0.f;
    if (colg < N_NODES) {
        off[colg] = e0 + (int)s[threadIdx.x];  // segment END
        float deg = (float)degq[threadIdx.x] * (1.0f / 32768.0f);
        dv = deg > 0.f ? 1.0f / sqrtf(deg) : 0.f;
        dinv[colg] = dv;
    }
    sdv[threadIdx.x] = dv;
    wptr[threadIdx.x] = e0 + (int)s[threadIdx.x] - (int)v;  // exclusive start
    __syncthreads();
    for (int i = threadIdx.x; i < cntb; i += 256) {
        ull rec = st[i];
        unsigned cl = (unsigned)(rec >> 32) & 255u;
        int pos = atomicAdd(&wptr[cl], 1);
        ed[pos] = (unsigned)rec;  // low 32 bits = r<<15 | q15
    }
    // fused xs: 256 nodes x 16 bf16-pairs
    int nb0 = b << 8;
    for (int idx = threadIdx.x; idx < 256 * 16; idx += 256) {
        int n = idx >> 4, c = idx & 15;
        int gn = nb0 + n;
        if (gn >= N_NODES) break;
        float d = sdv[n];
        xs[(size_t)gn * 16 + c] = packbf(x[(size_t)gn * 32 + 2 * c] * d,
                                         x[(size_t)gn * 32 + 2 * c + 1] * d);
    }
}

// ---------- active set (verbatim) ----------
__global__ __launch_bounds__(256) void activeset_k(const unsigned* __restrict__ ed,
                                                   const int* __restrict__ off,
                                                   int* __restrict__ mark,
                                                   int* __restrict__ list,
                                                   int* __restrict__ cnt) {
    int e = blockIdx.x * 256 + threadIdx.x;
    int end = off[NUM_APS - 1];
    if (e >= end) return;
    int r = (int)rec_r(ed[e]);
    if (atomicExch(&mark[r], 1) == 0) {
        int pos = atomicAdd(cnt, 1);
        if (pos < LISTCAP) list[pos] = r;
    }
}

// ---------- 32-feat gathers: 4 lanes/node, uint4 loads (verbatim round 14) ----------
__global__ __launch_bounds__(256) void gath32_dual_k(const unsigned* __restrict__ ed,
                                                     const int* __restrict__ off,
                                                     const float* __restrict__ dinv,
                                                     const uint4* __restrict__ src4,
                                                     uint4* __restrict__ p4,
                                                     uint4* __restrict__ u4, int nn) {
    int t = blockIdx.x * 256 + threadIdx.x;
    int n = t >> 2;
    if (n >= nn) return;
    int qd = t & 3;
    int s = (n == 0) ? 0 : off[n - 1];
    int e = off[n];
    float aA[8] = {0,0,0,0,0,0,0,0};
    float aB[8] = {0,0,0,0,0,0,0,0};
    float aC[8] = {0,0,0,0,0,0,0,0};
    float aD[8] = {0,0,0,0,0,0,0,0};
    int i = s;
    for (; i + 4 <= e; i += 4) {
        unsigned v0 = ed[i], v1 = ed[i + 1], v2 = ed[i + 2], v3 = ed[i + 3];
        uint4 s0 = src4[rec_r(v0) * 4 + qd];
        uint4 s1 = src4[rec_r(v1) * 4 + qd];
        uint4 s2 = src4[rec_r(v2) * 4 + qd];
        uint4 s3 = src4[rec_r(v3) * 4 + qd];
        float w0 = rec_w(v0), w1 = rec_w(v1), w2 = rec_w(v2), w3 = rec_w(v3);
        aA[0] += w0 * blo(s0.x); aA[1] += w0 * bhi(s0.x);
        aA[2] += w0 * blo(s0.y); aA[3] += w0 * bhi(s0.y);
        aA[4] += w0 * blo(s0.z); aA[5] += w0 * bhi(s0.z);
        aA[6] += w0 * blo(s0.w); aA[7] += w0 * bhi(s0.w);
        aB[0] += w1 * blo(s1.x); aB[1] += w1 * bhi(s1.x);
        aB[2] += w1 * blo(s1.y); aB[3] += w1 * bhi(s1.y);
        aB[4] += w1 * blo(s1.z); aB[5] += w1 * bhi(s1.z);
        aB[6] += w1 * blo(s1.w); aB[7] += w1 * bhi(s1.w);
        aC[0] += w2 * blo(s2.x); aC[1] += w2 * bhi(s2.x);
        aC[2] += w2 * blo(s2.y); aC[3] += w2 * bhi(s2.y);
        aC[4] += w2 * blo(s2.z); aC[5] += w2 * bhi(s2.z);
        aC[6] += w2 * blo(s2.w); aC[7] += w2 * bhi(s2.w);
        aD[0] += w3 * blo(s3.x); aD[1] += w3 * bhi(s3.x);
        aD[2] += w3 * blo(s3.y); aD[3] += w3 * bhi(s3.y);
        aD[4] += w3 * blo(s3.z); aD[5] += w3 * bhi(s3.z);
        aD[6] += w3 * blo(s3.w); aD[7] += w3 * bhi(s3.w);
    }
    for (; i < e; ++i) {
        unsigned v = ed[i];
        uint4 sv = src4[rec_r(v) * 4 + qd];
        float w = rec_w(v);
        aA[0] += w * blo(sv.x); aA[1] += w * bhi(sv.x);
        aA[2] += w * blo(sv.y); aA[3] += w * bhi(sv.y);
        aA[4] += w * blo(sv.z); aA[5] += w * bhi(sv.z);
        aA[6] += w * blo(sv.w); aA[7] += w * bhi(sv.w);
    }
#pragma unroll
    for (int k = 0; k < 8; ++k) aA[k] += aB[k] + aC[k] + aD[k];
    float d = dinv[n], d2 = d * d;
    p4[n * 4 + qd] = make_uint4(packbf(d * aA[0], d * aA[1]), packbf(d * aA[2], d * aA[3]),
                                packbf(d * aA[4], d * aA[5]), packbf(d * aA[6], d * aA[7]));
    u4[n * 4 + qd] = make_uint4(packbf(d2 * aA[0], d2 * aA[1]), packbf(d2 * aA[2], d2 * aA[3]),
                                packbf(d2 * aA[4], d2 * aA[5]), packbf(d2 * aA[6], d2 * aA[7]));
}

__global__ __launch_bounds__(256) void gath32_one_k(const unsigned* __restrict__ ed,
                                                    const int* __restrict__ off,
                                                    const float* __restrict__ dinv,
                                                    const uint4* __restrict__ src4,
                                                    uint4* __restrict__ p4, int nn) {
    int t = blockIdx.x * 256 + threadIdx.x;
    int n = t >> 2;
    if (n >= nn) return;
    int qd = t & 3;
    int s = (n == 0) ? 0 : off[n - 1];
    int e = off[n];
    float aA[8] = {0,0,0,0,0,0,0,0};
    float aB[8] = {0,0,0,0,0,0,0,0};
    float aC[8] = {0,0,0,0,0,0,0,0};
    float aD[8] = {0,0,0,0,0,0,0,0};
    int i = s;
    for (; i + 4 <= e; i += 4) {
        unsigned v0 = ed[i], v1 = ed[i + 1], v2 = ed[i + 2], v3 = ed[i + 3];
        uint4 s0 = src4[rec_r(v0) * 4 + qd];
        uint4 s1 = src4[rec_r(v1) * 4 + qd];
        uint4 s2 = src4[rec_r(v2) * 4 + qd];
        uint4 s3 = src4[rec_r(v3) * 4 + qd];
        float w0 = rec_w(v0), w1 = rec_w(v1), w2 = rec_w(v2), w3 = rec_w(v3);
        aA[0] += w0 * blo(s0.x); aA[1] += w0 * bhi(s0.x);
        aA[2] += w0 * blo(s0.y); aA[3] += w0 * bhi(s0.y);
        aA[4] += w0 * blo(s0.z); aA[5] += w0 * bhi(s0.z);
        aA[6] += w0 * blo(s0.w); aA[7] += w0 * bhi(s0.w);
        aB[0] += w1 * blo(s1.x); aB[1] += w1 * bhi(s1.x);
        aB[2] += w1 * blo(s1.y); aB[3] += w1 * bhi(s1.y);
        aB[4] += w1 * blo(s1.z); aB[5] += w1 * bhi(s1.z);
        aB[6] += w1 * blo(s1.w); aB[7] += w1 * bhi(s1.w);
        aC[0] += w2 * blo(s2.x); aC[1] += w2 * bhi(s2.x);
        aC[2] += w2 * blo(s2.y); aC[3] += w2 * bhi(s2.y);
        aC[4] += w2 * blo(s2.z); aC[5] += w2 * bhi(s2.z);
        aC[6] += w2 * blo(s2.w); aC[7] += w2 * bhi(s2.w);
        aD[0] += w3 * blo(s3.x); aD[1] += w3 * bhi(s3.x);
        aD[2] += w3 * blo(s3.y); aD[3] += w3 * bhi(s3.y);
        aD[4] += w3 * blo(s3.z); aD[5] += w3 * bhi(s3.z);
        aD[6] += w3 * blo(s3.w); aD[7] += w3 * bhi(s3.w);
    }
    for (; i < e; ++i) {
        unsigned v = ed[i];
        uint4 sv = src4[rec_r(v) * 4 + qd];
        float w = rec_w(v);
        aA[0] += w * blo(sv.x); aA[1] += w * bhi(sv.x);
        aA[2] += w * blo(sv.y); aA[3] += w * bhi(sv.y);
        aA[4] += w * blo(sv.z); aA[5] += w * bhi(sv.z);
        aA[6] += w * blo(sv.w); aA[7] += w * bhi(sv.w);
    }
#pragma unroll
    for (int k = 0; k < 8; ++k) aA[k] += aB[k] + aC[k] + aD[k];
    float d = dinv[n];
    p4[n * 4 + qd] = make_uint4(packbf(d * aA[0], d * aA[1]), packbf(d * aA[2], d * aA[3]),
                                packbf(d * aA[4], d * aA[5]), packbf(d * aA[6], d * aA[7]));
}

// ---------- 64-feat gathers (verbatim, pruned domain) ----------
__global__ __launch_bounds__(256) void gath64_q1_k(const unsigned* __restrict__ ed,
                                                   const int* __restrict__ off,
                                                   const float* __restrict__ dinv,
                                                   const unsigned* __restrict__ src,
                                                   unsigned* __restrict__ u,
                                                   unsigned* __restrict__ q, int nn) {
    int t = blockIdx.x * 256 + threadIdx.x;
    int n = t >> 5;
    if (n >= nn) return;
    int fp = t & 31;
    int s = (n == 0) ? 0 : off[n - 1];
    int e = off[n];
    float a0 = 0.f, a1 = 0.f, b0 = 0.f, b1 = 0.f;
    int i = s;
    for (; i + 4 <= e; i += 4) {
        unsigned v0 = ed[i], v1 = ed[i + 1], v2 = ed[i + 2], v3 = ed[i + 3];
        unsigned s0 = src[rec_r(v0) * 32 + fp];
        unsigned s1 = src[rec_r(v1) * 32 + fp];
        unsigned s2 = src[rec_r(v2) * 32 + fp];
        unsigned s3 = src[rec_r(v3) * 32 + fp];
        float w0 = rec_w(v0), w1 = rec_w(v1), w2 = rec_w(v2), w3 = rec_w(v3);
        a0 += w0 * blo(s0); a1 += w0 * bhi(s0);
        b0 += w1 * blo(s1); b1 += w1 * bhi(s1);
        a0 += w2 * blo(s2); a1 += w2 * bhi(s2);
        b0 += w3 * blo(s3); b1 += w3 * bhi(s3);
    }
    for (; i < e; ++i) {
        unsigned v = ed[i];
        unsigned sv = src[rec_r(v) * 32 + fp];
        float w = rec_w(v);
        a0 += w * blo(sv); a1 += w * bhi(sv);
    }
    a0 += b0; a1 += b1;
    float d = dinv[n], d2 = d * d;
    u[n * 32 + fp] = packbf(d2 * a0, d2 * a1);
    q[n * 32 + fp] = packbf(d * a0, d * a1);
}

__global__ __launch_bounds__(256) void gath64_act_k(const unsigned* __restrict__ ed,
                                                    const int* __restrict__ off,
                                                    const float* __restrict__ dinv,
                                                    const unsigned* __restrict__ src,
                                                    const int* __restrict__ list,
                                                    const int* __restrict__ cnt,
                                                    unsigned* __restrict__ u) {
    int t = blockIdx.x * 256 + threadIdx.x;
    int idx = t >> 5;
    int c = *cnt;
    if (c > LISTCAP) c = LISTCAP;
    if (idx >= c) return;
    int n = list[idx];
    int fp = t & 31;
    int s = (n == 0) ? 0 : off[n - 1];
    int e = off[n];
    float a0 = 0.f, a1 = 0.f, b0 = 0.f, b1 = 0.f;
    int i = s;
    for (; i + 4 <= e; i += 4) {
        unsigned v0 = ed[i], v1 = ed[i + 1], v2 = ed[i + 2], v3 = ed[i + 3];
        unsigned s0 = src[rec_r(v0) * 32 + fp];
        unsigned s1 = src[rec_r(v1) * 32 + fp];
        unsigned s2 = src[rec_r(v2) * 32 + fp];
        unsigned s3 = src[rec_r(v3) * 32 + fp];
        float w0 = rec_w(v0), w1 = rec_w(v1), w2 = rec_w(v2), w3 = rec_w(v3);
        a0 += w0 * blo(s0); a1 += w0 * bhi(s0);
        b0 += w1 * blo(s1); b1 += w1 * bhi(s1);
        a0 += w2 * blo(s2); a1 += w2 * bhi(s2);
        b0 += w3 * blo(s3); b1 += w3 * bhi(s3);
    }
    for (; i < e; ++i) {
        unsigned v = ed[i];
        unsigned sv = src[rec_r(v) * 32 + fp];
        float w = rec_w(v);
        a0 += w * blo(sv); a1 += w * bhi(sv);
    }
    a0 += b0; a1 += b1;
    float d = dinv[n], d2 = d * d;
    u[n * 32 + fp] = packbf(d2 * a0, d2 * a1);
}

__global__ __launch_bounds__(256) void gath64_one_k(const unsigned* __restrict__ ed,
                                                    const int* __restrict__ off,
                                                    const float* __restrict__ dinv,
                                                    const unsigned* __restrict__ src,
                                                    unsigned* __restrict__ q, int nn) {
    int t = blockIdx.x * 256 + threadIdx.x;
    int n = t >> 5;
    if (n >= nn) return;
    int fp = t & 31;
    int s = (n == 0) ? 0 : off[n - 1];
    int e = off[n];
    float a0 = 0.f, a1 = 0.f, b0 = 0.f, b1 = 0.f;
    int i = s;
    for (; i + 4 <= e; i += 4) {
        unsigned v0 = ed[i], v1 = ed[i + 1], v2 = ed[i + 2], v3 = ed[i + 3];
        unsigned s0 = src[rec_r(v0) * 32 + fp];
        unsigned s1 = src[rec_r(v1) * 32 + fp];
        unsigned s2 = src[rec_r(v2) * 32 + fp];
        unsigned s3 = src[rec_r(v3) * 32 + fp];
        float w0 = rec_w(v0), w1 = rec_w(v1), w2 = rec_w(v2), w3 = rec_w(v3);
        a0 += w0 * blo(s0); a1 += w0 * bhi(s0);
        b0 += w1 * blo(s1); b1 += w1 * bhi(s1);
        a0 += w2 * blo(s2); a1 += w2 * bhi(s2);
        b0 += w3 * blo(s3); b1 += w3 * bhi(s3);
    }
    for (; i < e; ++i) {
        unsigned v = ed[i];
        unsigned sv = src[rec_r(v) * 32 + fp];
        float w = rec_w(v);
        a0 += w * blo(sv); a1 += w * bhi(sv);
    }
    a0 += b0; a1 += b1;
    float d = dinv[n];
    q[n * 32 + fp] = packbf(d * a0, d * a1);
}

// ---------- dense layer 1 on MFMA (verbatim round 15, verified) ----------
__global__ __launch_bounds__(256) void dense1m_k(const float* __restrict__ x,
                                                 const unsigned* __restrict__ p1,
                                                 const unsigned* __restrict__ p2,
                                                 const float* __restrict__ w,
                                                 const float* __restrict__ b,
                                                 const float* __restrict__ dinv,
                                                 bf16* __restrict__ h1s,
                                                 bf16* __restrict__ h1p) {
    __shared__ short sxb[64 * 104];   // inputs bf16 [node][k], 13.3 KB
    __shared__ short swt[64 * 104];   // weights^T bf16 [col][k], 13.3 KB
    __shared__ float sbias[64];
    __shared__ float sdv[64];
    int tid = threadIdx.x;
    int nb = blockIdx.x * 64;
    for (int idx = tid; idx < 96 * 64; idx += 256) {
        int j = idx >> 6, f = idx & 63;
        swt[f * 104 + j] = f2bs(w[idx]);
    }
    for (int i = tid; i < 64 * 16; i += 256) {
        int n = i >> 4, c = i & 15;
        int gn = nb + n;
        float v0 = 0.f, v1 = 0.f;
        if (gn < N_NODES) {
            v0 = x[(size_t)gn * 32 + 2 * c];
            v1 = x[(size_t)gn * 32 + 2 * c + 1];
        }
        ((unsigned*)sxb)[n * 52 + c] = packbf(v0, v1);
    }
    for (int i = tid; i < 64 * 16; i += 256) {
        int n = i >> 4, c = i & 15;
        int gn = nb + n;
        unsigned v1 = 0u, v2 = 0u;
        if (gn < N_NODES) {
            v1 = p1[(size_t)gn * 16 + c];
            v2 = p2[(size_t)gn * 16 + c];
        }
        ((unsigned*)sxb)[n * 52 + 16 + c] = v1;
        ((unsigned*)sxb)[n * 52 + 32 + c] = v2;
    }
    if (tid < 64) {
        sbias[tid] = b[tid];
        int gn = nb + tid;
        sdv[tid] = (gn < N_NODES) ? dinv[gn] : 0.f;
    }
    __syncthreads();

    int lane = tid & 63;
    int wt = tid >> 6;
    int lr = lane & 15;
    int kg = lane >> 4;
    const short* arow = &sxb[(wt * 16 + lr) * 104 + kg * 8];
    bf16x8 a0 = *(const bf16x8*)(arow);
    bf16x8 a1 = *(const bf16x8*)(arow + 32);
    bf16x8 a2 = *(const bf16x8*)(arow + 64);
#pragma unroll
    for (int ct = 0; ct < 4; ++ct) {
        const short* bcol = &swt[(ct * 16 + lr) * 104 + kg * 8];
        bf16x8 b0 = *(const bf16x8*)(bcol);
        bf16x8 b1 = *(const bf16x8*)(bcol + 32);
        bf16x8 b2 = *(const bf16x8*)(bcol + 64);
        f32x4 acc = {0.f, 0.f, 0.f, 0.f};
        acc = __builtin_amdgcn_mfma_f32_16x16x32_bf16(a0, b0, acc, 0, 0, 0);
        acc = __builtin_amdgcn_mfma_f32_16x16x32_bf16(a1, b1, acc, 0, 0, 0);
        acc = __builtin_amdgcn_mfma_f32_16x16x32_bf16(a2, b2, acc, 0, 0, 0);
        int colo = ct * 16 + lr;
        float bias = sbias[colo];
#pragma unroll
        for (int r = 0; r < 4; ++r) {
            int rowl = wt * 16 + kg * 4 + r;
            int gn = nb + rowl;
            if (gn < N_NODES) {
                float a = acc[r] + bias;
                a = a > 0.f ? a : 0.01f * a;
                h1s[(size_t)gn * HID + colo] = __float2bfloat16(a * sdv[rowl]);
                if (gn < NUM_APS) h1p[(size_t)gn * HID + colo] = __float2bfloat16(a);
            }
        }
    }
}

// dense2 with fused logits heads (ap stays in LDS; out written directly)
__global__ __launch_bounds__(256) void dense2l_k(const bf16* __restrict__ h1p,
                                                 const bf16* __restrict__ q1,
                                                 const bf16* __restrict__ q2,
                                                 const float* __restrict__ w,
                                                 const float* __restrict__ b,
                                                 const float* __restrict__ wch,
                                                 const float* __restrict__ bch,
                                                 const float* __restrict__ wpw,
                                                 const float* __restrict__ bpw,
                                                 float* __restrict__ out) {
    __shared__ float sw[3 * HID * HID];  // 48 KB
    __shared__ float sx[4][3 * HID];
    __shared__ float sap[4][HID];
    for (int i = threadIdx.x; i < 3 * HID * HID; i += 256) sw[i] = w[i];
    int nb = blockIdx.x * 4;
    for (int k = threadIdx.x; k < 4 * 192; k += 256) {
        int ln = k / 192, j = k % 192;
        int n = nb + ln;
        float v = 0.f;
        if (n < NUM_APS) {
            int hop = j >> 6, ii = j & 63;
            const bf16* sp = (hop == 0) ? h1p : (hop == 1 ? q1 : q2);
            v = b2f(sp[n * HID + ii]);
        }
        sx[ln][j] = v;
    }
    __syncthreads();
    int ln = threadIdx.x >> 6;
    int f = threadIdx.x & 63;
    float acc = b[f];
#pragma unroll 8
    for (int j = 0; j < 192; ++j) acc += sx[ln][j] * sw[j * HID + f];
    acc = acc > 0.f ? acc : 0.01f * acc;
    sap[ln][f] = acc;
    __syncthreads();
    // heads: 24 threads, (node ln, head-col j)
    if (threadIdx.x < 24) {
        int lnn = threadIdx.x / 6, j = threadIdx.x % 6;
        int n = nb + lnn;
        if (n < NUM_APS) {
            const float* wp;
            float bb;
            float* o;
            if (j < 3) {
                wp = wch + j; bb = bch[j]; o = out + n * 3 + j;
            } else {
                int jj = j - 3;
                wp = wpw + jj; bb = bpw[jj]; o = out + NUM_APS * 3 + n * 3 + jj;
            }
            float a = bb;
#pragma unroll
            for (int i = 0; i < HID; ++i) a += sap[lnn][i] * wp[i * 3];
            *o = a;
        }
    }
}

extern "C" void kernel_launch(void* const* d_in, const int* in_sizes, int n_in,
                              void* d_out, int out_size, void* d_ws, size_t ws_size,
                              hipStream_t stream) {
    const float* x   = (const float*)d_in[0];
    const int*   ei  = (const int*)d_in[1];
    const float* ea  = (const float*)d_in[2];
    const float* w1  = (const float*)d_in[3];
    const float* b1  = (const float*)d_in[4];
    const float* w2  = (const float*)d_in[5];
    const float* b2  = (const float*)d_in[6];
    const float* wch = (const float*)d_in[7];
    const float* bch = (const float*)d_in[8];
    const float* wpw = (const float*)d_in[9];
    const float* bpw = (const float*)d_in[10];

    const int E = in_sizes[2];  // 1,600,000
    const int* row  = ei;
    const int* colv = ei + E;

    // ---- workspace layout (4-byte units), ~48.2 MB (verbatim round 15) ----
    float* ws = (float*)d_ws;
    ull*      staging = (ull*)ws;                     // [0, 3,603,456)
    int*      mark    = (int*)ws;                     // 100,000 ints (overlays staging)
    int*      acnt    = (int*)(ws + 100000);          // 1 int
    int*      alist   = (int*)(ws + 100001);          // LISTCAP ints
    unsigned* ed      = (unsigned*)(ws + 3700000);    // [3.7M, 5.3M)
    int*      binPtr  = (int*)(ws + 5300000);         // 512
    int*      binBase = (int*)(ws + 5300512);         // 512 (needs NB+1)
    int*      off     = (int*)(ws + 5301024);         // +100,000
    float*    dinv    = ws + 5401024;                 // +100,000
    unsigned* xs      = (unsigned*)(ws + 5501024);    // 1.6M (16B-aligned)
    unsigned* u1      = xs + 1600000;                 // 1.6M
    unsigned* p1      = (unsigned*)(ws + 8701024);    // 1.6M
    unsigned* p2      = p1 + 1600000;                 // 1.6M
    unsigned* h1s     = xs;                           // overlays xs∪u1 (3.2M)
    unsigned* u3      = p1;                           // overlays p1∪p2 (3.2M)
    bf16*     h1p     = (bf16*)(ws + 11901024);       // 32K units
    bf16*     q1      = (bf16*)(ws + 11933024);       // 32K
    bf16*     q2      = (bf16*)(ws + 11965024);       // 32K

    const int gridE = (E + EPB - 1) / EPB;  // 391

    // ---- hist-free binned CSR build (512-thread binwrite) ----
    hipMemsetAsync(binPtr, 0, 512 * sizeof(int), stream);
    binwrite2_k<<<gridE, 512, 0, stream>>>(row, colv, ea, binPtr, staging, E);
    binscan2_k<<<1, 512, 0, stream>>>(binPtr, binBase);
    binfin2x_k<<<NB, 256, 0, stream>>>(staging, binBase, x, ed, off, dinv, xs);

    // ---- active set (staging dead; mark/cnt reuse it) ----
    hipMemsetAsync(mark, 0, (N_NODES + 1) * sizeof(int), stream);  // mark + acnt
    activeset_k<<<128, 256, 0, stream>>>(ed, off, mark, alist, acnt);

    // ---- layer 1 ----
    gath32_dual_k<<<(N_NODES * 4 + 255) / 256, 256, 0, stream>>>(ed, off, dinv,
                                                                 (const uint4*)xs,
                                                                 (uint4*)p1, (uint4*)u1,
                                                                 N_NODES);
    gath32_one_k<<<(N_NODES * 4 + 255) / 256, 256, 0, stream>>>(ed, off, dinv,
                                                                (const uint4*)u1,
                                                                (uint4*)p2, N_NODES);
    dense1m_k<<<(N_NODES + 63) / 64, 256, 0, stream>>>(x, p1, p2, w1, b1, dinv,
                                                       (bf16*)h1s, h1p);

    // ---- layer 2: restricted to AP nodes + their in-neighbors ----
    gath64_q1_k<<<(NUM_APS * 32 + 255) / 256, 256, 0, stream>>>(ed, off, dinv, h1s,
                                                                u3, (unsigned*)q1,
                                                                NUM_APS);
    gath64_act_k<<<(LISTCAP * 32 + 255) / 256, 256, 0, stream>>>(ed, off, dinv, h1s,
                                                                 alist, acnt, u3);
    gath64_one_k<<<(NUM_APS * 32 + 255) / 256, 256, 0, stream>>>(ed, off, dinv, u3,
                                                                 (unsigned*)q2, NUM_APS);
    dense2l_k<<<(NUM_APS + 3) / 4, 256, 0, stream>>>(h1p, q1, q2, w2, b2,
                                                     wch, bch, wpw, bpw, (float*)d_out);
}

// Round 20
// 150.143 us; speedup vs baseline: 1.3561x; 1.0625x over previous
//
#include <hip/hip_runtime.h>
#include <hip/hip_bf16.h>

#define N_NODES 100000
#define NUM_APS 1000
#define IN_F 32
#define HID 64
#define NB 391      // bins of 256 cols: 391*256 = 100096 >= N_NODES
#define EPB 4096    // edges per block (keeps ~10.5-record bin tails -> merged writes)
#define CAPB 4608   // per-bin staging capacity (mean 4092, +8 sigma), guarded
#define LISTCAP 24000

typedef __hip_bfloat16 bf16;
typedef unsigned long long ull;
typedef __attribute__((ext_vector_type(8))) short bf16x8;
typedef __attribute__((ext_vector_type(4))) float f32x4;

__device__ __forceinline__ float b2f(bf16 v) { return __bfloat162float(v); }
__device__ __forceinline__ float blo(unsigned u) { return __uint_as_float(u << 16); }
__device__ __forceinline__ float bhi(unsigned u) { return __uint_as_float(u & 0xffff0000u); }
__device__ __forceinline__ unsigned packbf(float x, float y) {
    bf16 a = __float2bfloat16(x), b = __float2bfloat16(y);
    unsigned short ua = *reinterpret_cast<unsigned short*>(&a);
    unsigned short ub = *reinterpret_cast<unsigned short*>(&b);
    return (unsigned)ua | ((unsigned)ub << 16);
}
__device__ __forceinline__ short f2bs(float v) {
    bf16 t = __float2bfloat16(v);
    return *reinterpret_cast<short*>(&t);
}
// 4B edge record: r<<15 | q15(ew)
__device__ __forceinline__ unsigned rec_r(unsigned v) { return v >> 15; }
__device__ __forceinline__ float rec_w(unsigned v) { return (v & 32767u) * (1.f / 32768.f); }

// ---------- binned CSR build, hist-free (verbatim round 18) ----------
__global__ __launch_bounds__(512) void binwrite2_k(const int* __restrict__ row,
                                                   const int* __restrict__ col,
                                                   const float* __restrict__ ew,
                                                   int* __restrict__ binPtr,
                                                   ull* __restrict__ staging, int E) {
    __shared__ int h1[NB];
    __shared__ int base[NB];
    __shared__ int h2[NB];
    for (int i = threadIdx.x; i < NB; i += 512) { h1[i] = 0; h2[i] = 0; }
    __syncthreads();
    int e0 = blockIdx.x * EPB, e1 = min(e0 + EPB, E);
    for (int e = e0 + threadIdx.x; e < e1; e += 512) atomicAdd(&h1[col[e] >> 8], 1);
    __syncthreads();
    for (int i = threadIdx.x; i < NB; i += 512) {
        int v = h1[i];
        base[i] = v ? atomicAdd(&binPtr[i], v) : 0;
    }
    __syncthreads();
    for (int e = e0 + threadIdx.x; e < e1; e += 512) {
        int c = col[e];
        int b = c >> 8;
        int slot = atomicAdd(&h2[b], 1);
        unsigned q = (unsigned)(ew[e] * 32768.0f + 0.5f);
        if (q > 32767u) q = 32767u;
        ull rec = ((ull)(unsigned)(c & 255) << 32) |
                  (ull)(((unsigned)row[e] << 15) | q);
        int pos = base[b] + slot;
        if (pos < CAPB) staging[(size_t)b * CAPB + pos] = rec;
    }
}

__global__ __launch_bounds__(512) void binscan2_k(const int* __restrict__ binPtr,
                                                  int* __restrict__ binBase) {
    __shared__ int s[512];
    int v = (threadIdx.x < NB) ? min(binPtr[threadIdx.x], CAPB) : 0;
    s[threadIdx.x] = v;
    __syncthreads();
    for (int d = 1; d < 512; d <<= 1) {
        int t = (threadIdx.x >= d) ? s[threadIdx.x - d] : 0;
        __syncthreads();
        s[threadIdx.x] += t;
        __syncthreads();
    }
    if (threadIdx.x <= NB) binBase[threadIdx.x] = s[threadIdx.x] - v;
}

// binfin2x: bin sort + off/dinv AND fused xs = dinv ⊙ x (verbatim round 18)
__global__ __launch_bounds__(256) void binfin2x_k(const ull* __restrict__ staging,
                                                  const int* __restrict__ binBase,
                                                  const float* __restrict__ x,
                                                  unsigned* __restrict__ ed,
                                                  int* __restrict__ off,
                                                  float* __restrict__ dinv,
                                                  unsigned* __restrict__ xs) {
    __shared__ unsigned cnt[256];
    __shared__ unsigned degq[256];
    __shared__ int wptr[256];
    __shared__ unsigned s[256];
    __shared__ float sdv[256];
    int b = blockIdx.x;
    int e0 = binBase[b];
    int cntb = binBase[b + 1] - e0;
    const ull* st = staging + (size_t)b * CAPB;
    cnt[threadIdx.x] = 0;
    degq[threadIdx.x] = 0;
    __syncthreads();
    for (int i = threadIdx.x; i < cntb; i += 256) {
        ull rec = st[i];
        unsigned cl = (unsigned)(rec >> 32) & 255u;
        atomicAdd(&cnt[cl], 1u);
        atomicAdd(&degq[cl], (unsigned)rec & 32767u);
    }
    __syncthreads();
    unsigned v = cnt[threadIdx.x];
    s[threadIdx.x] = v;
    __syncthreads();
    for (int d = 1; d < 256; d <<= 1) {
        unsigned t = (threadIdx.x >= d) ? s[threadIdx.x - d] : 0;
        __syncthreads();
        s[threadIdx.x] += t;
        __syncthreads();
    }
    int colg = (b << 8) + threadIdx.x;
    float dv = 0.f;
    if (colg < N_NODES) {
        off[colg] = e0 + (int)s[threadIdx.x];  // segment END
        float deg = (float)degq[threadIdx.x] * (1.0f / 32768.0f);
        dv = deg > 0.f ? 1.0f / sqrtf(deg) : 0.f;
        dinv[colg] = dv;
    }
    sdv[threadIdx.x] = dv;
    wptr[threadIdx.x] = e0 + (int)s[threadIdx.x] - (int)v;  // exclusive start
    __syncthreads();
    for (int i = threadIdx.x; i < cntb; i += 256) {
        ull rec = st[i];
        unsigned cl = (unsigned)(rec >> 32) & 255u;
        int pos = atomicAdd(&wptr[cl], 1);
        ed[pos] = (unsigned)rec;  // low 32 bits = r<<15 | q15
    }
    // fused xs: 256 nodes x 16 bf16-pairs
    int nb0 = b << 8;
    for (int idx = threadIdx.x; idx < 256 * 16; idx += 256) {
        int n = idx >> 4, c = idx & 15;
        int gn = nb0 + n;
        if (gn >= N_NODES) break;
        float d = sdv[n];
        xs[(size_t)gn * 16 + c] = packbf(x[(size_t)gn * 32 + 2 * c] * d,
                                         x[(size_t)gn * 32 + 2 * c + 1] * d);
    }
}

// ---------- active set ----------
__global__ __launch_bounds__(256) void activeset_k(const unsigned* __restrict__ ed,
                                                   const int* __restrict__ off,
                                                   int* __restrict__ mark,
                                                   int* __restrict__ list,
                                                   int* __restrict__ cnt) {
    int e = blockIdx.x * 256 + threadIdx.x;
    int end = off[NUM_APS - 1];
    if (e >= end) return;
    int r = (int)rec_r(ed[e]);
    if (atomicExch(&mark[r], 1) == 0) {
        int pos = atomicAdd(cnt, 1);
        if (pos < LISTCAP) list[pos] = r;
    }
}

// ---------- 32-feat gathers: 4 lanes/node, uint4 loads ----------
__global__ __launch_bounds__(256) void gath32_dual_k(const unsigned* __restrict__ ed,
                                                     const int* __restrict__ off,
                                                     const float* __restrict__ dinv,
                                                     const uint4* __restrict__ src4,
                                                     uint4* __restrict__ p4,
                                                     uint4* __restrict__ u4, int nn) {
    int t = blockIdx.x * 256 + threadIdx.x;
    int n = t >> 2;
    if (n >= nn) return;
    int qd = t & 3;
    int s = (n == 0) ? 0 : off[n - 1];
    int e = off[n];
    float aA[8] = {0,0,0,0,0,0,0,0};
    float aB[8] = {0,0,0,0,0,0,0,0};
    float aC[8] = {0,0,0,0,0,0,0,0};
    float aD[8] = {0,0,0,0,0,0,0,0};
    int i = s;
    for (; i + 4 <= e; i += 4) {
        unsigned v0 = ed[i], v1 = ed[i + 1], v2 = ed[i + 2], v3 = ed[i + 3];
        uint4 s0 = src4[rec_r(v0) * 4 + qd];
        uint4 s1 = src4[rec_r(v1) * 4 + qd];
        uint4 s2 = src4[rec_r(v2) * 4 + qd];
        uint4 s3 = src4[rec_r(v3) * 4 + qd];
        float w0 = rec_w(v0), w1 = rec_w(v1), w2 = rec_w(v2), w3 = rec_w(v3);
        aA[0] += w0 * blo(s0.x); aA[1] += w0 * bhi(s0.x);
        aA[2] += w0 * blo(s0.y); aA[3] += w0 * bhi(s0.y);
        aA[4] += w0 * blo(s0.z); aA[5] += w0 * bhi(s0.z);
        aA[6] += w0 * blo(s0.w); aA[7] += w0 * bhi(s0.w);
        aB[0] += w1 * blo(s1.x); aB[1] += w1 * bhi(s1.x);
        aB[2] += w1 * blo(s1.y); aB[3] += w1 * bhi(s1.y);
        aB[4] += w1 * blo(s1.z); aB[5] += w1 * bhi(s1.z);
        aB[6] += w1 * blo(s1.w); aB[7] += w1 * bhi(s1.w);
        aC[0] += w2 * blo(s2.x); aC[1] += w2 * bhi(s2.x);
        aC[2] += w2 * blo(s2.y); aC[3] += w2 * bhi(s2.y);
        aC[4] += w2 * blo(s2.z); aC[5] += w2 * bhi(s2.z);
        aC[6] += w2 * blo(s2.w); aC[7] += w2 * bhi(s2.w);
        aD[0] += w3 * blo(s3.x); aD[1] += w3 * bhi(s3.x);
        aD[2] += w3 * blo(s3.y); aD[3] += w3 * bhi(s3.y);
        aD[4] += w3 * blo(s3.z); aD[5] += w3 * bhi(s3.z);
        aD[6] += w3 * blo(s3.w); aD[7] += w3 * bhi(s3.w);
    }
    for (; i < e; ++i) {
        unsigned v = ed[i];
        uint4 sv = src4[rec_r(v) * 4 + qd];
        float w = rec_w(v);
        aA[0] += w * blo(sv.x); aA[1] += w * bhi(sv.x);
        aA[2] += w * blo(sv.y); aA[3] += w * bhi(sv.y);
        aA[4] += w * blo(sv.z); aA[5] += w * bhi(sv.z);
        aA[6] += w * blo(sv.w); aA[7] += w * bhi(sv.w);
    }
#pragma unroll
    for (int k = 0; k < 8; ++k) aA[k] += aB[k] + aC[k] + aD[k];
    float d = dinv[n], d2 = d * d;
    p4[n * 4 + qd] = make_uint4(packbf(d * aA[0], d * aA[1]), packbf(d * aA[2], d * aA[3]),
                                packbf(d * aA[4], d * aA[5]), packbf(d * aA[6], d * aA[7]));
    u4[n * 4 + qd] = make_uint4(packbf(d2 * aA[0], d2 * aA[1]), packbf(d2 * aA[2], d2 * aA[3]),
                                packbf(d2 * aA[4], d2 * aA[5]), packbf(d2 * aA[6], d2 * aA[7]));
}

__global__ __launch_bounds__(256) void gath32_one_k(const unsigned* __restrict__ ed,
                                                    const int* __restrict__ off,
                                                    const float* __restrict__ dinv,
                                                    const uint4* __restrict__ src4,
                                                    uint4* __restrict__ p4, int nn) {
    int t = blockIdx.x * 256 + threadIdx.x;
    int n = t >> 2;
    if (n >= nn) return;
    int qd = t & 3;
    int s = (n == 0) ? 0 : off[n - 1];
    int e = off[n];
    float aA[8] = {0,0,0,0,0,0,0,0};
    float aB[8] = {0,0,0,0,0,0,0,0};
    float aC[8] = {0,0,0,0,0,0,0,0};
    float aD[8] = {0,0,0,0,0,0,0,0};
    int i = s;
    for (; i + 4 <= e; i += 4) {
        unsigned v0 = ed[i], v1 = ed[i + 1], v2 = ed[i + 2], v3 = ed[i + 3];
        uint4 s0 = src4[rec_r(v0) * 4 + qd];
        uint4 s1 = src4[rec_r(v1) * 4 + qd];
        uint4 s2 = src4[rec_r(v2) * 4 + qd];
        uint4 s3 = src4[rec_r(v3) * 4 + qd];
        float w0 = rec_w(v0), w1 = rec_w(v1), w2 = rec_w(v2), w3 = rec_w(v3);
        aA[0] += w0 * blo(s0.x); aA[1] += w0 * bhi(s0.x);
        aA[2] += w0 * blo(s0.y); aA[3] += w0 * bhi(s0.y);
        aA[4] += w0 * blo(s0.z); aA[5] += w0 * bhi(s0.z);
        aA[6] += w0 * blo(s0.w); aA[7] += w0 * bhi(s0.w);
        aB[0] += w1 * blo(s1.x); aB[1] += w1 * bhi(s1.x);
        aB[2] += w1 * blo(s1.y); aB[3] += w1 * bhi(s1.y);
        aB[4] += w1 * blo(s1.z); aB[5] += w1 * bhi(s1.z);
        aB[6] += w1 * blo(s1.w); aB[7] += w1 * bhi(s1.w);
        aC[0] += w2 * blo(s2.x); aC[1] += w2 * bhi(s2.x);
        aC[2] += w2 * blo(s2.y); aC[3] += w2 * bhi(s2.y);
        aC[4] += w2 * blo(s2.z); aC[5] += w2 * bhi(s2.z);
        aC[6] += w2 * blo(s2.w); aC[7] += w2 * bhi(s2.w);
        aD[0] += w3 * blo(s3.x); aD[1] += w3 * bhi(s3.x);
        aD[2] += w3 * blo(s3.y); aD[3] += w3 * bhi(s3.y);
        aD[4] += w3 * blo(s3.z); aD[5] += w3 * bhi(s3.z);
        aD[6] += w3 * blo(s3.w); aD[7] += w3 * bhi(s3.w);
    }
    for (; i < e; ++i) {
        unsigned v = ed[i];
        uint4 sv = src4[rec_r(v) * 4 + qd];
        float w = rec_w(v);
        aA[0] += w * blo(sv.x); aA[1] += w * bhi(sv.x);
        aA[2] += w * blo(sv.y); aA[3] += w * bhi(sv.y);
        aA[4] += w * blo(sv.z); aA[5] += w * bhi(sv.z);
        aA[6] += w * blo(sv.w); aA[7] += w * bhi(sv.w);
    }
#pragma unroll
    for (int k = 0; k < 8; ++k) aA[k] += aB[k] + aC[k] + aD[k];
    float d = dinv[n];
    p4[n * 4 + qd] = make_uint4(packbf(d * aA[0], d * aA[1]), packbf(d * aA[2], d * aA[3]),
                                packbf(d * aA[4], d * aA[5]), packbf(d * aA[6], d * aA[7]));
}

// ---------- fused layer-2 first hop: AP nodes (u3+q1) ∥ active-list nodes (u3) ----------
__global__ __launch_bounds__(256) void gath64_l2_k(const unsigned* __restrict__ ed,
                                                   const int* __restrict__ off,
                                                   const float* __restrict__ dinv,
                                                   const unsigned* __restrict__ src,
                                                   const int* __restrict__ list,
                                                   const int* __restrict__ cnt,
                                                   unsigned* __restrict__ u,
                                                   unsigned* __restrict__ q) {
    int t = blockIdx.x * 256 + threadIdx.x;
    int idx = t >> 5;
    int fp = t & 31;
    int n;
    bool wq;
    if (idx < NUM_APS) {
        n = idx;
        wq = true;
    } else {
        int j = idx - NUM_APS;
        int c = *cnt;
        if (c > LISTCAP) c = LISTCAP;
        if (j >= c) return;
        n = list[j];
        wq = false;
    }
    int s = (n == 0) ? 0 : off[n - 1];
    int e = off[n];
    float a0 = 0.f, a1 = 0.f, b0 = 0.f, b1 = 0.f;
    int i = s;
    for (; i + 4 <= e; i += 4) {
        unsigned v0 = ed[i], v1 = ed[i + 1], v2 = ed[i + 2], v3 = ed[i + 3];
        unsigned s0 = src[rec_r(v0) * 32 + fp];
        unsigned s1 = src[rec_r(v1) * 32 + fp];
        unsigned s2 = src[rec_r(v2) * 32 + fp];
        unsigned s3 = src[rec_r(v3) * 32 + fp];
        float w0 = rec_w(v0), w1 = rec_w(v1), w2 = rec_w(v2), w3 = rec_w(v3);
        a0 += w0 * blo(s0); a1 += w0 * bhi(s0);
        b0 += w1 * blo(s1); b1 += w1 * bhi(s1);
        a0 += w2 * blo(s2); a1 += w2 * bhi(s2);
        b0 += w3 * blo(s3); b1 += w3 * bhi(s3);
    }
    for (; i < e; ++i) {
        unsigned v = ed[i];
        unsigned sv = src[rec_r(v) * 32 + fp];
        float w = rec_w(v);
        a0 += w * blo(sv); a1 += w * bhi(sv);
    }
    a0 += b0; a1 += b1;
    float d = dinv[n], d2 = d * d;
    u[n * 32 + fp] = packbf(d2 * a0, d2 * a1);
    if (wq) q[n * 32 + fp] = packbf(d * a0, d * a1);
}

__global__ __launch_bounds__(256) void gath64_one_k(const unsigned* __restrict__ ed,
                                                    const int* __restrict__ off,
                                                    const float* __restrict__ dinv,
                                                    const unsigned* __restrict__ src,
                                                    unsigned* __restrict__ q, int nn) {
    int t = blockIdx.x * 256 + threadIdx.x;
    int n = t >> 5;
    if (n >= nn) return;
    int fp = t & 31;
    int s = (n == 0) ? 0 : off[n - 1];
    int e = off[n];
    float a0 = 0.f, a1 = 0.f, b0 = 0.f, b1 = 0.f;
    int i = s;
    for (; i + 4 <= e; i += 4) {
        unsigned v0 = ed[i], v1 = ed[i + 1], v2 = ed[i + 2], v3 = ed[i + 3];
        unsigned s0 = src[rec_r(v0) * 32 + fp];
        unsigned s1 = src[rec_r(v1) * 32 + fp];
        unsigned s2 = src[rec_r(v2) * 32 + fp];
        unsigned s3 = src[rec_r(v3) * 32 + fp];
        float w0 = rec_w(v0), w1 = rec_w(v1), w2 = rec_w(v2), w3 = rec_w(v3);
        a0 += w0 * blo(s0); a1 += w0 * bhi(s0);
        b0 += w1 * blo(s1); b1 += w1 * bhi(s1);
        a0 += w2 * blo(s2); a1 += w2 * bhi(s2);
        b0 += w3 * blo(s3); b1 += w3 * bhi(s3);
    }
    for (; i < e; ++i) {
        unsigned v = ed[i];
        unsigned sv = src[rec_r(v) * 32 + fp];
        float w = rec_w(v);
        a0 += w * blo(sv); a1 += w * bhi(sv);
    }
    a0 += b0; a1 += b1;
    float d = dinv[n];
    q[n * 32 + fp] = packbf(d * a0, d * a1);
}

// ---------- dense layer 1 on MFMA (verbatim round 15, verified) ----------
__global__ __launch_bounds__(256) void dense1m_k(const float* __restrict__ x,
                                                 const unsigned* __restrict__ p1,
                                                 const unsigned* __restrict__ p2,
                                                 const float* __restrict__ w,
                                                 const float* __restrict__ b,
                                                 const float* __restrict__ dinv,
                                                 bf16* __restrict__ h1s,
                                                 bf16* __restrict__ h1p) {
    __shared__ short sxb[64 * 104];   // inputs bf16 [node][k], 13.3 KB
    __shared__ short swt[64 * 104];   // weights^T bf16 [col][k], 13.3 KB
    __shared__ float sbias[64];
    __shared__ float sdv[64];
    int tid = threadIdx.x;
    int nb = blockIdx.x * 64;
    for (int idx = tid; idx < 96 * 64; idx += 256) {
        int j = idx >> 6, f = idx & 63;
        swt[f * 104 + j] = f2bs(w[idx]);
    }
    for (int i = tid; i < 64 * 16; i += 256) {
        int n = i >> 4, c = i & 15;
        int gn = nb + n;
        float v0 = 0.f, v1 = 0.f;
        if (gn < N_NODES) {
            v0 = x[(size_t)gn * 32 + 2 * c];
            v1 = x[(size_t)gn * 32 + 2 * c + 1];
        }
        ((unsigned*)sxb)[n * 52 + c] = packbf(v0, v1);
    }
    for (int i = tid; i < 64 * 16; i += 256) {
        int n = i >> 4, c = i & 15;
        int gn = nb + n;
        unsigned v1 = 0u, v2 = 0u;
        if (gn < N_NODES) {
            v1 = p1[(size_t)gn * 16 + c];
            v2 = p2[(size_t)gn * 16 + c];
        }
        ((unsigned*)sxb)[n * 52 + 16 + c] = v1;
        ((unsigned*)sxb)[n * 52 + 32 + c] = v2;
    }
    if (tid < 64) {
        sbias[tid] = b[tid];
        int gn = nb + tid;
        sdv[tid] = (gn < N_NODES) ? dinv[gn] : 0.f;
    }
    __syncthreads();

    int lane = tid & 63;
    int wt = tid >> 6;
    int lr = lane & 15;
    int kg = lane >> 4;
    const short* arow = &sxb[(wt * 16 + lr) * 104 + kg * 8];
    bf16x8 a0 = *(const bf16x8*)(arow);
    bf16x8 a1 = *(const bf16x8*)(arow + 32);
    bf16x8 a2 = *(const bf16x8*)(arow + 64);
#pragma unroll
    for (int ct = 0; ct < 4; ++ct) {
        const short* bcol = &swt[(ct * 16 + lr) * 104 + kg * 8];
        bf16x8 b0 = *(const bf16x8*)(bcol);
        bf16x8 b1 = *(const bf16x8*)(bcol + 32);
        bf16x8 b2 = *(const bf16x8*)(bcol + 64);
        f32x4 acc = {0.f, 0.f, 0.f, 0.f};
        acc = __builtin_amdgcn_mfma_f32_16x16x32_bf16(a0, b0, acc, 0, 0, 0);
        acc = __builtin_amdgcn_mfma_f32_16x16x32_bf16(a1, b1, acc, 0, 0, 0);
        acc = __builtin_amdgcn_mfma_f32_16x16x32_bf16(a2, b2, acc, 0, 0, 0);
        int colo = ct * 16 + lr;
        float bias = sbias[colo];
#pragma unroll
        for (int r = 0; r < 4; ++r) {
            int rowl = wt * 16 + kg * 4 + r;
            int gn = nb + rowl;
            if (gn < N_NODES) {
                float a = acc[r] + bias;
                a = a > 0.f ? a : 0.01f * a;
                h1s[(size_t)gn * HID + colo] = __float2bfloat16(a * sdv[rowl]);
                if (gn < NUM_APS) h1p[(size_t)gn * HID + colo] = __float2bfloat16(a);
            }
        }
    }
}

// dense2 with fused logits heads (verbatim round 18)
__global__ __launch_bounds__(256) void dense2l_k(const bf16* __restrict__ h1p,
                                                 const bf16* __restrict__ q1,
                                                 const bf16* __restrict__ q2,
                                                 const float* __restrict__ w,
                                                 const float* __restrict__ b,
                                                 const float* __restrict__ wch,
                                                 const float* __restrict__ bch,
                                                 const float* __restrict__ wpw,
                                                 const float* __restrict__ bpw,
                                                 float* __restrict__ out) {
    __shared__ float sw[3 * HID * HID];  // 48 KB
    __shared__ float sx[4][3 * HID];
    __shared__ float sap[4][HID];
    for (int i = threadIdx.x; i < 3 * HID * HID; i += 256) sw[i] = w[i];
    int nb = blockIdx.x * 4;
    for (int k = threadIdx.x; k < 4 * 192; k += 256) {
        int ln = k / 192, j = k % 192;
        int n = nb + ln;
        float v = 0.f;
        if (n < NUM_APS) {
            int hop = j >> 6, ii = j & 63;
            const bf16* sp = (hop == 0) ? h1p : (hop == 1 ? q1 : q2);
            v = b2f(sp[n * HID + ii]);
        }
        sx[ln][j] = v;
    }
    __syncthreads();
    int ln = threadIdx.x >> 6;
    int f = threadIdx.x & 63;
    float acc = b[f];
#pragma unroll 8
    for (int j = 0; j < 192; ++j) acc += sx[ln][j] * sw[j * HID + f];
    acc = acc > 0.f ? acc : 0.01f * acc;
    sap[ln][f] = acc;
    __syncthreads();
    if (threadIdx.x < 24) {
        int lnn = threadIdx.x / 6, j = threadIdx.x % 6;
        int n = nb + lnn;
        if (n < NUM_APS) {
            const float* wp;
            float bb;
            float* o;
            if (j < 3) {
                wp = wch + j; bb = bch[j]; o = out + n * 3 + j;
            } else {
                int jj = j - 3;
                wp = wpw + jj; bb = bpw[jj]; o = out + NUM_APS * 3 + n * 3 + jj;
            }
            float a = bb;
#pragma unroll
            for (int i = 0; i < HID; ++i) a += sap[lnn][i] * wp[i * 3];
            *o = a;
        }
    }
}

extern "C" void kernel_launch(void* const* d_in, const int* in_sizes, int n_in,
                              void* d_out, int out_size, void* d_ws, size_t ws_size,
                              hipStream_t stream) {
    const float* x   = (const float*)d_in[0];
    const int*   ei  = (const int*)d_in[1];
    const float* ea  = (const float*)d_in[2];
    const float* w1  = (const float*)d_in[3];
    const float* b1  = (const float*)d_in[4];
    const float* w2  = (const float*)d_in[5];
    const float* b2  = (const float*)d_in[6];
    const float* wch = (const float*)d_in[7];
    const float* bch = (const float*)d_in[8];
    const float* wpw = (const float*)d_in[9];
    const float* bpw = (const float*)d_in[10];

    const int E = in_sizes[2];  // 1,600,000
    const int* row  = ei;
    const int* colv = ei + E;

    // ---- workspace layout (4-byte units), ~48.5 MB ----
    // FIXED vs round 19: h1p/q1/q2 each get 32,000 float units (64,000 bf16).
    float* ws = (float*)d_ws;
    ull*      staging = (ull*)ws;                     // [0, 3,603,456)
    unsigned* ed      = (unsigned*)(ws + 3700000);    // [3.7M, 5.3M)
    int*      binPtr  = (int*)(ws + 5300000);         // 512
    int*      acnt    = (int*)(ws + 5300512);         // 1
    int*      mark    = (int*)(ws + 5300513);         // 100,000 -> ends 5,400,513
    int*      binBase = (int*)(ws + 5401024);         // 512 (needs NB+1)
    int*      off     = (int*)(ws + 5402048);         // +100,000
    float*    dinv    = ws + 5502048;                 // +100,000
    unsigned* xs      = (unsigned*)(ws + 5602048);    // 1.6M (16B-aligned)
    unsigned* u1      = xs + 1600000;                 // 1.6M
    unsigned* p1      = (unsigned*)(ws + 8802048);    // 1.6M (16B-aligned)
    unsigned* p2      = p1 + 1600000;                 // 1.6M
    unsigned* h1s     = xs;                           // overlays xs∪u1 (3.2M)
    unsigned* u3      = p1;                           // overlays p1∪p2 (3.2M)
    bf16*     h1p     = (bf16*)(ws + 12002048);       // 64,000 bf16 = 32,000 floats
    bf16*     q1      = (bf16*)(ws + 12034048);       // 64,000 bf16
    bf16*     q2      = (bf16*)(ws + 12066048);       // 64,000 bf16
    int*      alist   = (int*)(ws + 12098048);        // LISTCAP ints -> ends 12,122,048

    const int gridE = (E + EPB - 1) / EPB;  // 391

    // ---- single memset: binPtr + acnt + mark ----
    hipMemsetAsync(binPtr, 0, 100513 * sizeof(int), stream);

    // ---- hist-free binned CSR build (512-thread binwrite) ----
    binwrite2_k<<<gridE, 512, 0, stream>>>(row, colv, ea, binPtr, staging, E);
    binscan2_k<<<1, 512, 0, stream>>>(binPtr, binBase);
    binfin2x_k<<<NB, 256, 0, stream>>>(staging, binBase, x, ed, off, dinv, xs);

    // ---- active set ----
    activeset_k<<<128, 256, 0, stream>>>(ed, off, mark, alist, acnt);

    // ---- layer 1 ----
    gath32_dual_k<<<(N_NODES * 4 + 255) / 256, 256, 0, stream>>>(ed, off, dinv,
                                                                 (const uint4*)xs,
                                                                 (uint4*)p1, (uint4*)u1,
                                                                 N_NODES);
    gath32_one_k<<<(N_NODES * 4 + 255) / 256, 256, 0, stream>>>(ed, off, dinv,
                                                                (const uint4*)u1,
                                                                (uint4*)p2, N_NODES);
    dense1m_k<<<(N_NODES + 63) / 64, 256, 0, stream>>>(x, p1, p2, w1, b1, dinv,
                                                       (bf16*)h1s, h1p);

    // ---- layer 2: fused AP + active-list first hop, then q2, then dense+heads ----
    gath64_l2_k<<<((NUM_APS + LISTCAP) * 32 + 255) / 256, 256, 0, stream>>>(
        ed, off, dinv, h1s, alist, acnt, u3, (unsigned*)q1);
    gath64_one_k<<<(NUM_APS * 32 + 255) / 256, 256, 0, stream>>>(ed, off, dinv, u3,
                                                                 (unsigned*)q2, NUM_APS);
    dense2l_k<<<(NUM_APS + 3) / 4, 256, 0, stream>>>(h1p, q1, q2, w2, b2,
                                                     wch, bch, wpw, bpw, (float*)d_out);
}

// Round 21
// 148.391 us; speedup vs baseline: 1.3721x; 1.0118x over previous
//
#include <hip/hip_runtime.h>
#include <hip/hip_bf16.h>

#define N_NODES 100000
#define NUM_APS 1000
#define IN_F 32
#define HID 64
#define NB 391      // bins of 256 cols: 391*256 = 100096 >= N_NODES
#define EPB 4096    // edges per block (keeps ~10.5-record bin tails -> merged writes)
#define CAPB 4608   // per-bin staging capacity (mean 4092, +8 sigma), guarded
#define LISTCAP 24000
#define ZERON 100513  // binPtr(512) + acnt(1) + mark(100000)

typedef __hip_bfloat16 bf16;
typedef unsigned long long ull;
typedef __attribute__((ext_vector_type(8))) short bf16x8;
typedef __attribute__((ext_vector_type(4))) float f32x4;

__device__ __forceinline__ float b2f(bf16 v) { return __bfloat162float(v); }
__device__ __forceinline__ float blo(unsigned u) { return __uint_as_float(u << 16); }
__device__ __forceinline__ float bhi(unsigned u) { return __uint_as_float(u & 0xffff0000u); }
__device__ __forceinline__ unsigned packbf(float x, float y) {
    bf16 a = __float2bfloat16(x), b = __float2bfloat16(y);
    unsigned short ua = *reinterpret_cast<unsigned short*>(&a);
    unsigned short ub = *reinterpret_cast<unsigned short*>(&b);
    return (unsigned)ua | ((unsigned)ub << 16);
}
__device__ __forceinline__ short f2bs(float v) {
    bf16 t = __float2bfloat16(v);
    return *reinterpret_cast<short*>(&t);
}
// 4B edge record: r<<15 | q15(ew)
__device__ __forceinline__ unsigned rec_r(unsigned v) { return v >> 15; }
__device__ __forceinline__ float rec_w(unsigned v) { return (v & 32767u) * (1.f / 32768.f); }

// custom zero kernel: rocclr fillBufferAligned costs ~41 us FIXED (measured
// rounds 15/18/20); this does the same 402 KB in ~2 us.
__global__ void zero_k(int* __restrict__ p) {
    int i = blockIdx.x * 256 + threadIdx.x;
    if (i < ZERON) p[i] = 0;
}

// ---------- binned CSR build, hist-free (verbatim round 20) ----------
__global__ __launch_bounds__(512) void binwrite2_k(const int* __restrict__ row,
                                                   const int* __restrict__ col,
                                                   const float* __restrict__ ew,
                                                   int* __restrict__ binPtr,
                                                   ull* __restrict__ staging, int E) {
    __shared__ int h1[NB];
    __shared__ int base[NB];
    __shared__ int h2[NB];
    for (int i = threadIdx.x; i < NB; i += 512) { h1[i] = 0; h2[i] = 0; }
    __syncthreads();
    int e0 = blockIdx.x * EPB, e1 = min(e0 + EPB, E);
    for (int e = e0 + threadIdx.x; e < e1; e += 512) atomicAdd(&h1[col[e] >> 8], 1);
    __syncthreads();
    for (int i = threadIdx.x; i < NB; i += 512) {
        int v = h1[i];
        base[i] = v ? atomicAdd(&binPtr[i], v) : 0;
    }
    __syncthreads();
    for (int e = e0 + threadIdx.x; e < e1; e += 512) {
        int c = col[e];
        int b = c >> 8;
        int slot = atomicAdd(&h2[b], 1);
        unsigned q = (unsigned)(ew[e] * 32768.0f + 0.5f);
        if (q > 32767u) q = 32767u;
        ull rec = ((ull)(unsigned)(c & 255) << 32) |
                  (ull)(((unsigned)row[e] << 15) | q);
        int pos = base[b] + slot;
        if (pos < CAPB) staging[(size_t)b * CAPB + pos] = rec;
    }
}

__global__ __launch_bounds__(512) void binscan2_k(const int* __restrict__ binPtr,
                                                  int* __restrict__ binBase) {
    __shared__ int s[512];
    int v = (threadIdx.x < NB) ? min(binPtr[threadIdx.x], CAPB) : 0;
    s[threadIdx.x] = v;
    __syncthreads();
    for (int d = 1; d < 512; d <<= 1) {
        int t = (threadIdx.x >= d) ? s[threadIdx.x - d] : 0;
        __syncthreads();
        s[threadIdx.x] += t;
        __syncthreads();
    }
    if (threadIdx.x <= NB) binBase[threadIdx.x] = s[threadIdx.x] - v;
}

// binfin2x: bin sort + off/dinv AND fused xs = dinv ⊙ x (verbatim round 20)
__global__ __launch_bounds__(256) void binfin2x_k(const ull* __restrict__ staging,
                                                  const int* __restrict__ binBase,
                                                  const float* __restrict__ x,
                                                  unsigned* __restrict__ ed,
                                                  int* __restrict__ off,
                                                  float* __restrict__ dinv,
                                                  unsigned* __restrict__ xs) {
    __shared__ unsigned cnt[256];
    __shared__ unsigned degq[256];
    __shared__ int wptr[256];
    __shared__ unsigned s[256];
    __shared__ float sdv[256];
    int b = blockIdx.x;
    int e0 = binBase[b];
    int cntb = binBase[b + 1] - e0;
    const ull* st = staging + (size_t)b * CAPB;
    cnt[threadIdx.x] = 0;
    degq[threadIdx.x] = 0;
    __syncthreads();
    for (int i = threadIdx.x; i < cntb; i += 256) {
        ull rec = st[i];
        unsigned cl = (unsigned)(rec >> 32) & 255u;
        atomicAdd(&cnt[cl], 1u);
        atomicAdd(&degq[cl], (unsigned)rec & 32767u);
    }
    __syncthreads();
    unsigned v = cnt[threadIdx.x];
    s[threadIdx.x] = v;
    __syncthreads();
    for (int d = 1; d < 256; d <<= 1) {
        unsigned t = (threadIdx.x >= d) ? s[threadIdx.x - d] : 0;
        __syncthreads();
        s[threadIdx.x] += t;
        __syncthreads();
    }
    int colg = (b << 8) + threadIdx.x;
    float dv = 0.f;
    if (colg < N_NODES) {
        off[colg] = e0 + (int)s[threadIdx.x];  // segment END
        float deg = (float)degq[threadIdx.x] * (1.0f / 32768.0f);
        dv = deg > 0.f ? 1.0f / sqrtf(deg) : 0.f;
        dinv[colg] = dv;
    }
    sdv[threadIdx.x] = dv;
    wptr[threadIdx.x] = e0 + (int)s[threadIdx.x] - (int)v;  // exclusive start
    __syncthreads();
    for (int i = threadIdx.x; i < cntb; i += 256) {
        ull rec = st[i];
        unsigned cl = (unsigned)(rec >> 32) & 255u;
        int pos = atomicAdd(&wptr[cl], 1);
        ed[pos] = (unsigned)rec;  // low 32 bits = r<<15 | q15
    }
    // fused xs: 256 nodes x 16 bf16-pairs
    int nb0 = b << 8;
    for (int idx = threadIdx.x; idx < 256 * 16; idx += 256) {
        int n = idx >> 4, c = idx & 15;
        int gn = nb0 + n;
        if (gn >= N_NODES) break;
        float d = sdv[n];
        xs[(size_t)gn * 16 + c] = packbf(x[(size_t)gn * 32 + 2 * c] * d,
                                         x[(size_t)gn * 32 + 2 * c + 1] * d);
    }
}

// ---------- active set (verbatim) ----------
__global__ __launch_bounds__(256) void activeset_k(const unsigned* __restrict__ ed,
                                                   const int* __restrict__ off,
                                                   int* __restrict__ mark,
                                                   int* __restrict__ list,
                                                   int* __restrict__ cnt) {
    int e = blockIdx.x * 256 + threadIdx.x;
    int end = off[NUM_APS - 1];
    if (e >= end) return;
    int r = (int)rec_r(ed[e]);
    if (atomicExch(&mark[r], 1) == 0) {
        int pos = atomicAdd(cnt, 1);
        if (pos < LISTCAP) list[pos] = r;
    }
}

// ---------- 32-feat gathers: 4 lanes/node, uint4 loads (verbatim) ----------
__global__ __launch_bounds__(256) void gath32_dual_k(const unsigned* __restrict__ ed,
                                                     const int* __restrict__ off,
                                                     const float* __restrict__ dinv,
                                                     const uint4* __restrict__ src4,
                                                     uint4* __restrict__ p4,
                                                     uint4* __restrict__ u4, int nn) {
    int t = blockIdx.x * 256 + threadIdx.x;
    int n = t >> 2;
    if (n >= nn) return;
    int qd = t & 3;
    int s = (n == 0) ? 0 : off[n - 1];
    int e = off[n];
    float aA[8] = {0,0,0,0,0,0,0,0};
    float aB[8] = {0,0,0,0,0,0,0,0};
    float aC[8] = {0,0,0,0,0,0,0,0};
    float aD[8] = {0,0,0,0,0,0,0,0};
    int i = s;
    for (; i + 4 <= e; i += 4) {
        unsigned v0 = ed[i], v1 = ed[i + 1], v2 = ed[i + 2], v3 = ed[i + 3];
        uint4 s0 = src4[rec_r(v0) * 4 + qd];
        uint4 s1 = src4[rec_r(v1) * 4 + qd];
        uint4 s2 = src4[rec_r(v2) * 4 + qd];
        uint4 s3 = src4[rec_r(v3) * 4 + qd];
        float w0 = rec_w(v0), w1 = rec_w(v1), w2 = rec_w(v2), w3 = rec_w(v3);
        aA[0] += w0 * blo(s0.x); aA[1] += w0 * bhi(s0.x);
        aA[2] += w0 * blo(s0.y); aA[3] += w0 * bhi(s0.y);
        aA[4] += w0 * blo(s0.z); aA[5] += w0 * bhi(s0.z);
        aA[6] += w0 * blo(s0.w); aA[7] += w0 * bhi(s0.w);
        aB[0] += w1 * blo(s1.x); aB[1] += w1 * bhi(s1.x);
        aB[2] += w1 * blo(s1.y); aB[3] += w1 * bhi(s1.y);
        aB[4] += w1 * blo(s1.z); aB[5] += w1 * bhi(s1.z);
        aB[6] += w1 * blo(s1.w); aB[7] += w1 * bhi(s1.w);
        aC[0] += w2 * blo(s2.x); aC[1] += w2 * bhi(s2.x);
        aC[2] += w2 * blo(s2.y); aC[3] += w2 * bhi(s2.y);
        aC[4] += w2 * blo(s2.z); aC[5] += w2 * bhi(s2.z);
        aC[6] += w2 * blo(s2.w); aC[7] += w2 * bhi(s2.w);
        aD[0] += w3 * blo(s3.x); aD[1] += w3 * bhi(s3.x);
        aD[2] += w3 * blo(s3.y); aD[3] += w3 * bhi(s3.y);
        aD[4] += w3 * blo(s3.z); aD[5] += w3 * bhi(s3.z);
        aD[6] += w3 * blo(s3.w); aD[7] += w3 * bhi(s3.w);
    }
    for (; i < e; ++i) {
        unsigned v = ed[i];
        uint4 sv = src4[rec_r(v) * 4 + qd];
        float w = rec_w(v);
        aA[0] += w * blo(sv.x); aA[1] += w * bhi(sv.x);
        aA[2] += w * blo(sv.y); aA[3] += w * bhi(sv.y);
        aA[4] += w * blo(sv.z); aA[5] += w * bhi(sv.z);
        aA[6] += w * blo(sv.w); aA[7] += w * bhi(sv.w);
    }
#pragma unroll
    for (int k = 0; k < 8; ++k) aA[k] += aB[k] + aC[k] + aD[k];
    float d = dinv[n], d2 = d * d;
    p4[n * 4 + qd] = make_uint4(packbf(d * aA[0], d * aA[1]), packbf(d * aA[2], d * aA[3]),
                                packbf(d * aA[4], d * aA[5]), packbf(d * aA[6], d * aA[7]));
    u4[n * 4 + qd] = make_uint4(packbf(d2 * aA[0], d2 * aA[1]), packbf(d2 * aA[2], d2 * aA[3]),
                                packbf(d2 * aA[4], d2 * aA[5]), packbf(d2 * aA[6], d2 * aA[7]));
}

__global__ __launch_bounds__(256) void gath32_one_k(const unsigned* __restrict__ ed,
                                                    const int* __restrict__ off,
                                                    const float* __restrict__ dinv,
                                                    const uint4* __restrict__ src4,
                                                    uint4* __restrict__ p4, int nn) {
    int t = blockIdx.x * 256 + threadIdx.x;
    int n = t >> 2;
    if (n >= nn) return;
    int qd = t & 3;
    int s = (n == 0) ? 0 : off[n - 1];
    int e = off[n];
    float aA[8] = {0,0,0,0,0,0,0,0};
    float aB[8] = {0,0,0,0,0,0,0,0};
    float aC[8] = {0,0,0,0,0,0,0,0};
    float aD[8] = {0,0,0,0,0,0,0,0};
    int i = s;
    for (; i + 4 <= e; i += 4) {
        unsigned v0 = ed[i], v1 = ed[i + 1], v2 = ed[i + 2], v3 = ed[i + 3];
        uint4 s0 = src4[rec_r(v0) * 4 + qd];
        uint4 s1 = src4[rec_r(v1) * 4 + qd];
        uint4 s2 = src4[rec_r(v2) * 4 + qd];
        uint4 s3 = src4[rec_r(v3) * 4 + qd];
        float w0 = rec_w(v0), w1 = rec_w(v1), w2 = rec_w(v2), w3 = rec_w(v3);
        aA[0] += w0 * blo(s0.x); aA[1] += w0 * bhi(s0.x);
        aA[2] += w0 * blo(s0.y); aA[3] += w0 * bhi(s0.y);
        aA[4] += w0 * blo(s0.z); aA[5] += w0 * bhi(s0.z);
        aA[6] += w0 * blo(s0.w); aA[7] += w0 * bhi(s0.w);
        aB[0] += w1 * blo(s1.x); aB[1] += w1 * bhi(s1.x);
        aB[2] += w1 * blo(s1.y); aB[3] += w1 * bhi(s1.y);
        aB[4] += w1 * blo(s1.z); aB[5] += w1 * bhi(s1.z);
        aB[6] += w1 * blo(s1.w); aB[7] += w1 * bhi(s1.w);
        aC[0] += w2 * blo(s2.x); aC[1] += w2 * bhi(s2.x);
        aC[2] += w2 * blo(s2.y); aC[3] += w2 * bhi(s2.y);
        aC[4] += w2 * blo(s2.z); aC[5] += w2 * bhi(s2.z);
        aC[6] += w2 * blo(s2.w); aC[7] += w2 * bhi(s2.w);
        aD[0] += w3 * blo(s3.x); aD[1] += w3 * bhi(s3.x);
        aD[2] += w3 * blo(s3.y); aD[3] += w3 * bhi(s3.y);
        aD[4] += w3 * blo(s3.z); aD[5] += w3 * bhi(s3.z);
        aD[6] += w3 * blo(s3.w); aD[7] += w3 * bhi(s3.w);
    }
    for (; i < e; ++i) {
        unsigned v = ed[i];
        uint4 sv = src4[rec_r(v) * 4 + qd];
        float w = rec_w(v);
        aA[0] += w * blo(sv.x); aA[1] += w * bhi(sv.x);
        aA[2] += w * blo(sv.y); aA[3] += w * bhi(sv.y);
        aA[4] += w * blo(sv.z); aA[5] += w * bhi(sv.z);
        aA[6] += w * blo(sv.w); aA[7] += w * bhi(sv.w);
    }
#pragma unroll
    for (int k = 0; k < 8; ++k) aA[k] += aB[k] + aC[k] + aD[k];
    float d = dinv[n];
    p4[n * 4 + qd] = make_uint4(packbf(d * aA[0], d * aA[1]), packbf(d * aA[2], d * aA[3]),
                                packbf(d * aA[4], d * aA[5]), packbf(d * aA[6], d * aA[7]));
}

// ---------- fused layer-2 first hop: AP nodes (u3+q1) ∥ active-list nodes (u3) ----------
__global__ __launch_bounds__(256) void gath64_l2_k(const unsigned* __restrict__ ed,
                                                   const int* __restrict__ off,
                                                   const float* __restrict__ dinv,
                                                   const unsigned* __restrict__ src,
                                                   const int* __restrict__ list,
                                                   const int* __restrict__ cnt,
                                                   unsigned* __restrict__ u,
                                                   unsigned* __restrict__ q) {
    int t = blockIdx.x * 256 + threadIdx.x;
    int idx = t >> 5;
    int fp = t & 31;
    int n;
    bool wq;
    if (idx < NUM_APS) {
        n = idx;
        wq = true;
    } else {
        int j = idx - NUM_APS;
        int c = *cnt;
        if (c > LISTCAP) c = LISTCAP;
        if (j >= c) return;
        n = list[j];
        wq = false;
    }
    int s = (n == 0) ? 0 : off[n - 1];
    int e = off[n];
    float a0 = 0.f, a1 = 0.f, b0 = 0.f, b1 = 0.f;
    int i = s;
    for (; i + 4 <= e; i += 4) {
        unsigned v0 = ed[i], v1 = ed[i + 1], v2 = ed[i + 2], v3 = ed[i + 3];
        unsigned s0 = src[rec_r(v0) * 32 + fp];
        unsigned s1 = src[rec_r(v1) * 32 + fp];
        unsigned s2 = src[rec_r(v2) * 32 + fp];
        unsigned s3 = src[rec_r(v3) * 32 + fp];
        float w0 = rec_w(v0), w1 = rec_w(v1), w2 = rec_w(v2), w3 = rec_w(v3);
        a0 += w0 * blo(s0); a1 += w0 * bhi(s0);
        b0 += w1 * blo(s1); b1 += w1 * bhi(s1);
        a0 += w2 * blo(s2); a1 += w2 * bhi(s2);
        b0 += w3 * blo(s3); b1 += w3 * bhi(s3);
    }
    for (; i < e; ++i) {
        unsigned v = ed[i];
        unsigned sv = src[rec_r(v) * 32 + fp];
        float w = rec_w(v);
        a0 += w * blo(sv); a1 += w * bhi(sv);
    }
    a0 += b0; a1 += b1;
    float d = dinv[n], d2 = d * d;
    u[n * 32 + fp] = packbf(d2 * a0, d2 * a1);
    if (wq) q[n * 32 + fp] = packbf(d * a0, d * a1);
}

__global__ __launch_bounds__(256) void gath64_one_k(const unsigned* __restrict__ ed,
                                                    const int* __restrict__ off,
                                                    const float* __restrict__ dinv,
                                                    const unsigned* __restrict__ src,
                                                    unsigned* __restrict__ q, int nn) {
    int t = blockIdx.x * 256 + threadIdx.x;
    int n = t >> 5;
    if (n >= nn) return;
    int fp = t & 31;
    int s = (n == 0) ? 0 : off[n - 1];
    int e = off[n];
    float a0 = 0.f, a1 = 0.f, b0 = 0.f, b1 = 0.f;
    int i = s;
    for (; i + 4 <= e; i += 4) {
        unsigned v0 = ed[i], v1 = ed[i + 1], v2 = ed[i + 2], v3 = ed[i + 3];
        unsigned s0 = src[rec_r(v0) * 32 + fp];
        unsigned s1 = src[rec_r(v1) * 32 + fp];
        unsigned s2 = src[rec_r(v2) * 32 + fp];
        unsigned s3 = src[rec_r(v3) * 32 + fp];
        float w0 = rec_w(v0), w1 = rec_w(v1), w2 = rec_w(v2), w3 = rec_w(v3);
        a0 += w0 * blo(s0); a1 += w0 * bhi(s0);
        b0 += w1 * blo(s1); b1 += w1 * bhi(s1);
        a0 += w2 * blo(s2); a1 += w2 * bhi(s2);
        b0 += w3 * blo(s3); b1 += w3 * bhi(s3);
    }
    for (; i < e; ++i) {
        unsigned v = ed[i];
        unsigned sv = src[rec_r(v) * 32 + fp];
        float w = rec_w(v);
        a0 += w * blo(sv); a1 += w * bhi(sv);
    }
    a0 += b0; a1 += b1;
    float d = dinv[n];
    q[n * 32 + fp] = packbf(d * a0, d * a1);
}

// ---------- dense layer 1 on MFMA (verbatim round 15, verified) ----------
__global__ __launch_bounds__(256) void dense1m_k(const float* __restrict__ x,
                                                 const unsigned* __restrict__ p1,
                                                 const unsigned* __restrict__ p2,
                                                 const float* __restrict__ w,
                                                 const float* __restrict__ b,
                                                 const float* __restrict__ dinv,
                                                 bf16* __restrict__ h1s,
                                                 bf16* __restrict__ h1p) {
    __shared__ short sxb[64 * 104];   // inputs bf16 [node][k], 13.3 KB
    __shared__ short swt[64 * 104];   // weights^T bf16 [col][k], 13.3 KB
    __shared__ float sbias[64];
    __shared__ float sdv[64];
    int tid = threadIdx.x;
    int nb = blockIdx.x * 64;
    for (int idx = tid; idx < 96 * 64; idx += 256) {
        int j = idx >> 6, f = idx & 63;
        swt[f * 104 + j] = f2bs(w[idx]);
    }
    for (int i = tid; i < 64 * 16; i += 256) {
        int n = i >> 4, c = i & 15;
        int gn = nb + n;
        float v0 = 0.f, v1 = 0.f;
        if (gn < N_NODES) {
            v0 = x[(size_t)gn * 32 + 2 * c];
            v1 = x[(size_t)gn * 32 + 2 * c + 1];
        }
        ((unsigned*)sxb)[n * 52 + c] = packbf(v0, v1);
    }
    for (int i = tid; i < 64 * 16; i += 256) {
        int n = i >> 4, c = i & 15;
        int gn = nb + n;
        unsigned v1 = 0u, v2 = 0u;
        if (gn < N_NODES) {
            v1 = p1[(size_t)gn * 16 + c];
            v2 = p2[(size_t)gn * 16 + c];
        }
        ((unsigned*)sxb)[n * 52 + 16 + c] = v1;
        ((unsigned*)sxb)[n * 52 + 32 + c] = v2;
    }
    if (tid < 64) {
        sbias[tid] = b[tid];
        int gn = nb + tid;
        sdv[tid] = (gn < N_NODES) ? dinv[gn] : 0.f;
    }
    __syncthreads();

    int lane = tid & 63;
    int wt = tid >> 6;
    int lr = lane & 15;
    int kg = lane >> 4;
    const short* arow = &sxb[(wt * 16 + lr) * 104 + kg * 8];
    bf16x8 a0 = *(const bf16x8*)(arow);
    bf16x8 a1 = *(const bf16x8*)(arow + 32);
    bf16x8 a2 = *(const bf16x8*)(arow + 64);
#pragma unroll
    for (int ct = 0; ct < 4; ++ct) {
        const short* bcol = &swt[(ct * 16 + lr) * 104 + kg * 8];
        bf16x8 b0 = *(const bf16x8*)(bcol);
        bf16x8 b1 = *(const bf16x8*)(bcol + 32);
        bf16x8 b2 = *(const bf16x8*)(bcol + 64);
        f32x4 acc = {0.f, 0.f, 0.f, 0.f};
        acc = __builtin_amdgcn_mfma_f32_16x16x32_bf16(a0, b0, acc, 0, 0, 0);
        acc = __builtin_amdgcn_mfma_f32_16x16x32_bf16(a1, b1, acc, 0, 0, 0);
        acc = __builtin_amdgcn_mfma_f32_16x16x32_bf16(a2, b2, acc, 0, 0, 0);
        int colo = ct * 16 + lr;
        float bias = sbias[colo];
#pragma unroll
        for (int r = 0; r < 4; ++r) {
            int rowl = wt * 16 + kg * 4 + r;
            int gn = nb + rowl;
            if (gn < N_NODES) {
                float a = acc[r] + bias;
                a = a > 0.f ? a : 0.01f * a;
                h1s[(size_t)gn * HID + colo] = __float2bfloat16(a * sdv[rowl]);
                if (gn < NUM_APS) h1p[(size_t)gn * HID + colo] = __float2bfloat16(a);
            }
        }
    }
}

// dense2 with fused logits heads (verbatim round 18/20)
__global__ __launch_bounds__(256) void dense2l_k(const bf16* __restrict__ h1p,
                                                 const bf16* __restrict__ q1,
                                                 const bf16* __restrict__ q2,
                                                 const float* __restrict__ w,
                                                 const float* __restrict__ b,
                                                 const float* __restrict__ wch,
                                                 const float* __restrict__ bch,
                                                 const float* __restrict__ wpw,
                                                 const float* __restrict__ bpw,
                                                 float* __restrict__ out) {
    __shared__ float sw[3 * HID * HID];  // 48 KB
    __shared__ float sx[4][3 * HID];
    __shared__ float sap[4][HID];
    for (int i = threadIdx.x; i < 3 * HID * HID; i += 256) sw[i] = w[i];
    int nb = blockIdx.x * 4;
    for (int k = threadIdx.x; k < 4 * 192; k += 256) {
        int ln = k / 192, j = k % 192;
        int n = nb + ln;
        float v = 0.f;
        if (n < NUM_APS) {
            int hop = j >> 6, ii = j & 63;
            const bf16* sp = (hop == 0) ? h1p : (hop == 1 ? q1 : q2);
            v = b2f(sp[n * HID + ii]);
        }
        sx[ln][j] = v;
    }
    __syncthreads();
    int ln = threadIdx.x >> 6;
    int f = threadIdx.x & 63;
    float acc = b[f];
#pragma unroll 8
    for (int j = 0; j < 192; ++j) acc += sx[ln][j] * sw[j * HID + f];
    acc = acc > 0.f ? acc : 0.01f * acc;
    sap[ln][f] = acc;
    __syncthreads();
    if (threadIdx.x < 24) {
        int lnn = threadIdx.x / 6, j = threadIdx.x % 6;
        int n = nb + lnn;
        if (n < NUM_APS) {
            const float* wp;
            float bb;
            float* o;
            if (j < 3) {
                wp = wch + j; bb = bch[j]; o = out + n * 3 + j;
            } else {
                int jj = j - 3;
                wp = wpw + jj; bb = bpw[jj]; o = out + NUM_APS * 3 + n * 3 + jj;
            }
            float a = bb;
#pragma unroll
            for (int i = 0; i < HID; ++i) a += sap[lnn][i] * wp[i * 3];
            *o = a;
        }
    }
}

extern "C" void kernel_launch(void* const* d_in, const int* in_sizes, int n_in,
                              void* d_out, int out_size, void* d_ws, size_t ws_size,
                              hipStream_t stream) {
    const float* x   = (const float*)d_in[0];
    const int*   ei  = (const int*)d_in[1];
    const float* ea  = (const float*)d_in[2];
    const float* w1  = (const float*)d_in[3];
    const float* b1  = (const float*)d_in[4];
    const float* w2  = (const float*)d_in[5];
    const float* b2  = (const float*)d_in[6];
    const float* wch = (const float*)d_in[7];
    const float* bch = (const float*)d_in[8];
    const float* wpw = (const float*)d_in[9];
    const float* bpw = (const float*)d_in[10];

    const int E = in_sizes[2];  // 1,600,000
    const int* row  = ei;
    const int* colv = ei + E;

    // ---- workspace layout (4-byte units), ~48.5 MB (verbatim round 20) ----
    float* ws = (float*)d_ws;
    ull*      staging = (ull*)ws;                     // [0, 3,603,456)
    unsigned* ed      = (unsigned*)(ws + 3700000);    // [3.7M, 5.3M)
    int*      binPtr  = (int*)(ws + 5300000);         // 512
    int*      acnt    = (int*)(ws + 5300512);         // 1
    int*      mark    = (int*)(ws + 5300513);         // 100,000 -> ends 5,400,513
    int*      binBase = (int*)(ws + 5401024);         // 512 (needs NB+1)
    int*      off     = (int*)(ws + 5402048);         // +100,000
    float*    dinv    = ws + 5502048;                 // +100,000
    unsigned* xs      = (unsigned*)(ws + 5602048);    // 1.6M (16B-aligned)
    unsigned* u1      = xs + 1600000;                 // 1.6M
    unsigned* p1      = (unsigned*)(ws + 8802048);    // 1.6M (16B-aligned)
    unsigned* p2      = p1 + 1600000;                 // 1.6M
    unsigned* h1s     = xs;                           // overlays xs∪u1 (3.2M)
    unsigned* u3      = p1;                           // overlays p1∪p2 (3.2M)
    bf16*     h1p     = (bf16*)(ws + 12002048);       // 64,000 bf16 = 32,000 floats
    bf16*     q1      = (bf16*)(ws + 12034048);       // 64,000 bf16
    bf16*     q2      = (bf16*)(ws + 12066048);       // 64,000 bf16
    int*      alist   = (int*)(ws + 12098048);        // LISTCAP ints

    const int gridE = (E + EPB - 1) / EPB;  // 391

    // ---- custom zero (replaces ~41 us rocclr fill): binPtr + acnt + mark ----
    zero_k<<<(ZERON + 255) / 256, 256, 0, stream>>>(binPtr);

    // ---- hist-free binned CSR build (512-thread binwrite) ----
    binwrite2_k<<<gridE, 512, 0, stream>>>(row, colv, ea, binPtr, staging, E);
    binscan2_k<<<1, 512, 0, stream>>>(binPtr, binBase);
    binfin2x_k<<<NB, 256, 0, stream>>>(staging, binBase, x, ed, off, dinv, xs);

    // ---- active set ----
    activeset_k<<<128, 256, 0, stream>>>(ed, off, mark, alist, acnt);

    // ---- layer 1 ----
    gath32_dual_k<<<(N_NODES * 4 + 255) / 256, 256, 0, stream>>>(ed, off, dinv,
                                                                 (const uint4*)xs,
                                                                 (uint4*)p1, (uint4*)u1,
                                                                 N_NODES);
    gath32_one_k<<<(N_NODES * 4 + 255) / 256, 256, 0, stream>>>(ed, off, dinv,
                                                                (const uint4*)u1,
                                                                (uint4*)p2, N_NODES);
    dense1m_k<<<(N_NODES + 63) / 64, 256, 0, stream>>>(x, p1, p2, w1, b1, dinv,
                                                       (bf16*)h1s, h1p);

    // ---- layer 2: fused AP + active-list first hop, then q2, then dense+heads ----
    gath64_l2_k<<<((NUM_APS + LISTCAP) * 32 + 255) / 256, 256, 0, stream>>>(
        ed, off, dinv, h1s, alist, acnt, u3, (unsigned*)q1);
    gath64_one_k<<<(NUM_APS * 32 + 255) / 256, 256, 0, stream>>>(ed, off, dinv, u3,
                                                                 (unsigned*)q2, NUM_APS);
    dense2l_k<<<(NUM_APS + 3) / 4, 256, 0, stream>>>(h1p, q1, q2, w2, b2,
                                                     wch, bch, wpw, bpw, (float*)d_out);
}